// Round 15
// baseline (182.152 us; speedup 1.0000x reference)
//
#include <hip/hip_runtime.h>
#include <hip/hip_bf16.h>
#include <math.h>

#define B_ 16
#define T_ 12
#define N_ 325
#define DIMS_ 40
#define DAYS_ 288
#define MW 12          // bitmask words per mask row (11 used, 1 pad)
#define NQP 336        // padded q-rows for mask (21*16)
#define VP 352         // padded v/ct-row stride for transposed bf16 arrays (11*32)

typedef __attribute__((ext_vector_type(8))) short bf16x8;
typedef __attribute__((ext_vector_type(4))) float f32x4;

__device__ __forceinline__ unsigned short cvt1(float f){
  unsigned w;
  asm("v_cvt_pk_bf16_f32 %0, %1, %2" : "=v"(w) : "v"(f), "v"(f));
  return (unsigned short)w;
}
__device__ __forceinline__ unsigned cvt2(float a, float b){
  unsigned w;
  asm("v_cvt_pk_bf16_f32 %0, %1, %2" : "=v"(w) : "v"(a), "v"(b));
  return w;
}
__device__ __forceinline__ bf16x8 u2b(uint4 u){ return __builtin_bit_cast(bf16x8, u); }

// ---------------- fused setup ----------------
// blocks 0-15: dg_a1 | 16-31: mask_bits (inline dtype detect) | 32: p3 transpose
// blocks 33-35: weight prep (Wc/bc/Wcb, Wallb, Wpb)
__global__ void setup_k(const float* __restrict__ p1, const float* __restrict__ pk,
                        const int* __restrict__ ind, float* __restrict__ A1,
                        const unsigned char* __restrict__ raw, unsigned* __restrict__ bm,
                        const float* __restrict__ p3, float* __restrict__ p3t,
                        const float* W_gcn, const float* b_gcn, const float* W_r2, const float* b_r2,
                        const float* Wtq, const float* Wtk, const float* Wtv,
                        const float* Wgq, const float* Wgk, const float* Wgv,
                        const float* W_proj,
                        float* bc, unsigned short* Wcb, unsigned short* Wallb,
                        unsigned short* Wpb){
  int tid = threadIdx.x;
  if (blockIdx.x < 16){
    int b = blockIdx.x;
    __shared__ float te[DIMS_];
    int day = ind[b] % DAYS_; if (day < 0) day += DAYS_;
    for (int i = tid; i < DIMS_; i += blockDim.x) te[i] = p1[day*DIMS_ + i];
    __syncthreads();
    for (int jk = tid; jk < DIMS_*DIMS_; jk += blockDim.x){
      float acc = 0.f;
      for (int i = 0; i < DIMS_; ++i) acc += te[i] * pk[i*DIMS_*DIMS_ + jk];
      A1[b*DIMS_*DIMS_ + jk] = acc;
    }
  } else if (blockIdx.x < 32){
    __shared__ int f1, f3, fo;
    if (tid == 0){ f1 = 0; f3 = 0; fo = 0; }
    __syncthreads();
    for (int i = tid; i < 4096; i += 256){
      unsigned char v = raw[i];
      int m4 = i & 3;
      if (v == 0x3F && m4 == 1) atomicOr(&f1, 1);
      if (v == 0x3F && m4 == 3) atomicOr(&f3, 1);
      if (v != 0 && m4 != 0)    atomicOr(&fo, 1);
    }
    __syncthreads();
    int mode = f1 ? 2 : (f3 ? 3 : (fo ? 0 : 1));
    int idx = (blockIdx.x - 16) * 256 + tid;
    if (idx >= NQP * MW) return;
    int q = idx / MW, w = idx % MW;
    if (q >= N_) { bm[idx] = 0xFFFFFFFFu; return; }
    unsigned bits = 0;
    for (int j = 0; j < 32; ++j){
      int k = w*32 + j;
      int v;
      if (k >= N_) v = 1;
      else {
        size_t i = (size_t)q*N_ + k;
        if (mode == 0)      v = raw[i] != 0;
        else if (mode == 1) v = ((const int*)raw)[i] != 0;
        else if (mode == 2) { unsigned short u = ((const unsigned short*)raw)[i]; v = (u & 0x7FFF) != 0; }
        else                { float f = ((const float*)raw)[i]; v = (f != 0.f); }
      }
      bits |= (unsigned)v << j;
    }
    bm[idx] = bits;
  } else if (blockIdx.x == 32){
    for (int idx = tid; idx < DIMS_*N_; idx += 256){
      int k = idx / N_, c = idx % N_;
      p3t[idx] = p3[c*DIMS_ + k];
    }
  } else if (blockIdx.x == 33){
    __shared__ float WcS[64*96];
    for (int idx = tid; idx < 64*96; idx += 256){
      int d = idx / 96, c = idx % 96;
      float acc = 0.f;
      for (int o = 0; o < 32; ++o) acc += W_r2[d*32 + o] * W_gcn[o*96 + c];
      WcS[idx] = acc;
    }
    for (int d = tid; d < 64; d += 256){
      float acc = b_r2[d];
      for (int o = 0; o < 32; ++o) acc += W_r2[d*32 + o] * b_gcn[o];
      bc[d] = acc;
    }
    __syncthreads();
    for (int idx = tid; idx < 3*4*64*8; idx += 256){
      int jj = idx & 7, rest = idx >> 3;
      int d = rest % 64, gk = rest / 64;
      int g = gk & 3, kc = gk >> 2;
      Wcb[idx] = cvt1(WcS[d*96 + kc*32 + g*8 + jj]);
    }
  } else if (blockIdx.x == 34){
    for (int idx = tid; idx < 2*4*144*8; idx += 256){
      int jj = idx & 7, rest = idx >> 3;
      int j = rest % 144, gk = rest / 144;
      int g = gk & 3, kc = gk >> 2;
      int dd = kc*32 + g*8 + jj;
      const float* src; int rsrc;
      if      (j < 16) { src = Wtq; rsrc = j; }
      else if (j < 32) { src = Wtk; rsrc = j - 16; }
      else if (j < 48) { src = Wtv; rsrc = j - 32; }
      else if (j < 80) { src = Wgq; rsrc = j - 48; }
      else if (j < 112){ src = Wgk; rsrc = j - 80; }
      else             { src = Wgv; rsrc = j - 112; }
      Wallb[idx] = cvt1(src[rsrc*64 + dd]);
    }
  } else {
    for (int idx = tid; idx < 2*4*64*8; idx += 256){
      int jj = idx & 7, rest = idx >> 3;
      int d = rest % 64, gk = rest / 64;
      int g = gk & 3, kc = gk >> 2;
      int k = kc*32 + g*8 + jj;
      Wpb[idx] = (k < 48) ? cvt1(W_proj[d*48 + k]) : (unsigned short)0;
    }
  }
}

// ---------------- mid_k: blocks [0,1152) hproj MFMA (direct W_r1); [1152,2452) dg_adp wave-level ----------------
__global__ __launch_bounds__(256) void mid_k(const float* __restrict__ x,
                                             const float* __restrict__ W_r1,
                                             const float* __restrict__ b_r1,
                                             unsigned short* __restrict__ ht,
                                             unsigned short* __restrict__ hn,
                                             const float* __restrict__ p2,
                                             const float* __restrict__ p3t,
                                             const float* __restrict__ A1,
                                             unsigned short* __restrict__ adp_bf){
  __shared__ float t2s[4][DIMS_];
  int tid = threadIdx.x, wv = tid >> 6, ln = tid & 63;
  int bid = blockIdx.x;
  if (bid < 1152){
    // ---- hproj (math identical to round 14; W_r1 read + RNE cvt in-kernel) ----
    int bt = bid / 6;
    int nt = (bid % 6)*4 + wv;
    if (nt >= 21) return;
    int g = ln >> 4, r = ln & 15;
    int n0 = nt*16;
    int nc = min(n0 + r, N_-1);
    int b = bt / T_, t = bt % T_;
    const float* xrow = x + ((size_t)bt*N_ + nc)*64;
    float4 xa = *(const float4*)&xrow[g*8];
    float4 xb = *(const float4*)&xrow[g*8 + 4];
    uint4 u0 = { cvt2(xa.x,xa.y), cvt2(xa.z,xa.w), cvt2(xb.x,xb.y), cvt2(xb.z,xb.w) };
    bf16x8 bv0 = u2b(u0);
    float4 xc = *(const float4*)&xrow[32 + g*8];
    float4 xd = *(const float4*)&xrow[32 + g*8 + 4];
    uint4 u1 = { cvt2(xc.x,xc.y), cvt2(xc.z,xc.w), cvt2(xd.x,xd.y), cvt2(xd.z,xd.w) };
    bf16x8 bv1 = u2b(u1);
    int n = n0 + r;
    #pragma unroll
    for (int ct = 0; ct < 2; ++ct){
      const float* wrow = W_r1 + (ct*16 + r)*64;
      float4 wa = *(const float4*)&wrow[g*8];
      float4 wb = *(const float4*)&wrow[g*8 + 4];
      uint4 ua = { cvt2(wa.x,wa.y), cvt2(wa.z,wa.w), cvt2(wb.x,wb.y), cvt2(wb.z,wb.w) };
      bf16x8 a0 = u2b(ua);
      float4 wc = *(const float4*)&wrow[32 + g*8];
      float4 wd = *(const float4*)&wrow[32 + g*8 + 4];
      uint4 ub = { cvt2(wc.x,wc.y), cvt2(wc.z,wc.w), cvt2(wd.x,wd.y), cvt2(wd.z,wd.w) };
      bf16x8 a1 = u2b(ub);
      f32x4 acc = {0.f,0.f,0.f,0.f};
      acc = __builtin_amdgcn_mfma_f32_16x16x32_bf16(a0, bv0, acc, 0,0,0);
      acc = __builtin_amdgcn_mfma_f32_16x16x32_bf16(a1, bv1, acc, 0,0,0);
      if (n < N_){
        float v0 = acc[0] + b_r1[ct*16 + g*4 + 0];
        float v1 = acc[1] + b_r1[ct*16 + g*4 + 1];
        float v2 = acc[2] + b_r1[ct*16 + g*4 + 2];
        float v3 = acc[3] + b_r1[ct*16 + g*4 + 3];
        int c0 = ct*16 + g*4;
        ht[((size_t)b*384 + t*32 + c0+0)*VP + n] = cvt1(v0);
        ht[((size_t)b*384 + t*32 + c0+1)*VP + n] = cvt1(v1);
        ht[((size_t)b*384 + t*32 + c0+2)*VP + n] = cvt1(v2);
        ht[((size_t)b*384 + t*32 + c0+3)*VP + n] = cvt1(v3);
        uint2 hp = { cvt2(v0, v1), cvt2(v2, v3) };
        *(uint2*)&hn[((size_t)b*N_ + n)*384 + t*32 + c0] = hp;
      }
    }
  } else {
    // ---- dg_adp, one n per wave ----
    int p = (bid - 1152)*4 + wv;            // < 5200
    int b = p / N_, n = p % N_;
    // t2[j] = sum_jj p2[n][jj] * A1[b][jj][j]   (lanes j<40)
    const float* a1 = A1 + b*DIMS_*DIMS_;
    const float* p2r = p2 + n*DIMS_;
    if (ln < DIMS_){
      float acc = 0.f;
      for (int jj = 0; jj < DIMS_; ++jj) acc += p2r[jj] * a1[jj*DIMS_ + ln];
      t2s[wv][ln] = acc;
    }
    // same-wave LDS write->read is in-order; no barrier needed
    float sc[6];
    float lm = -1e30f;
    #pragma unroll
    for (int i = 0; i < 6; ++i){
      int c = ln + i*64;
      float acc = 0.f;
      if (c < N_){
        for (int k = 0; k < DIMS_; ++k) acc += p3t[k*N_ + c] * t2s[wv][k];
        acc = fmaxf(acc, 0.f);
        lm = fmaxf(lm, acc);
      }
      sc[i] = acc;
    }
    #pragma unroll
    for (int off = 32; off; off >>= 1) lm = fmaxf(lm, __shfl_xor(lm, off));
    float ls = 0.f;
    #pragma unroll
    for (int i = 0; i < 6; ++i){
      int c = ln + i*64;
      if (c < N_){ float e = __expf(sc[i] - lm); sc[i] = e; ls += e; }
    }
    #pragma unroll
    for (int off = 32; off; off >>= 1) ls += __shfl_xor(ls, off);
    float inv = 1.f / ls;
    unsigned short* outp = adp_bf + ((size_t)b*N_ + n) * VP;
    #pragma unroll
    for (int i = 0; i < 6; ++i){
      int c = ln + i*64;
      if (c < VP) outp[c] = (c < N_) ? cvt1(sc[i] * inv) : (unsigned short)0;
    }
  }
}

// ---------------- GCN hop as MFMA GEMM; out_t (transposed, nullable) + out_n (row-major) ----------------
__global__ __launch_bounds__(256) void gcn_mfma(const unsigned short* __restrict__ adp_bf,
                                                const unsigned short* __restrict__ in_t,
                                                unsigned short* __restrict__ out_t,
                                                unsigned short* __restrict__ out_n){
  int bi = blockIdx.x;
  int b = bi / 36, rest = bi % 36;
  int wt = rest / 6, ctb = rest % 6;
  int tid = threadIdx.x, wv = tid >> 6, ln = tid & 63, g = ln >> 4, r = ln & 15;
  int w0 = wt*64 + wv*16;
  int ct0 = ctb*64;
  int wr = min(w0 + r, N_-1);
  const unsigned short* arow  = adp_bf + ((size_t)b*N_ + wr)*VP;
  const unsigned short* bbase = in_t  + ((size_t)b*384 + ct0)*VP;
  f32x4 acc0={0.f,0.f,0.f,0.f}, acc1=acc0, acc2=acc0, acc3=acc0;
  #pragma unroll
  for (int ks = 0; ks < 11; ++ks){
    int ko = ks*32 + g*8;
    bf16x8 a  = *(const bf16x8*)&arow[ko];
    bf16x8 b0 = *(const bf16x8*)&bbase[(size_t)( 0 + r)*VP + ko];
    bf16x8 b1 = *(const bf16x8*)&bbase[(size_t)(16 + r)*VP + ko];
    bf16x8 b2 = *(const bf16x8*)&bbase[(size_t)(32 + r)*VP + ko];
    bf16x8 b3 = *(const bf16x8*)&bbase[(size_t)(48 + r)*VP + ko];
    acc0 = __builtin_amdgcn_mfma_f32_16x16x32_bf16(a, b0, acc0, 0,0,0);
    acc1 = __builtin_amdgcn_mfma_f32_16x16x32_bf16(a, b1, acc1, 0,0,0);
    acc2 = __builtin_amdgcn_mfma_f32_16x16x32_bf16(a, b2, acc2, 0,0,0);
    acc3 = __builtin_amdgcn_mfma_f32_16x16x32_bf16(a, b3, acc3, 0,0,0);
  }
  f32x4 av[4] = {acc0, acc1, acc2, acc3};
  if (out_t && w0 + 15 < VP){
    #pragma unroll
    for (int dt = 0; dt < 4; ++dt){
      int ct = ct0 + dt*16 + r;
      uint2 pk2 = { cvt2(av[dt][0], av[dt][1]), cvt2(av[dt][2], av[dt][3]) };
      *(uint2*)&out_t[((size_t)b*384 + ct)*VP + w0 + g*4] = pk2;
    }
  }
  #pragma unroll
  for (int dt = 0; dt < 4; ++dt){
    int ct = ct0 + dt*16 + r;
    #pragma unroll
    for (int rg = 0; rg < 4; ++rg){
      int w = w0 + g*4 + rg;
      if (w < N_) out_n[((size_t)b*N_ + w)*384 + ct] = cvt1(av[dt][rg]);
    }
  }
}

// ---------------- xg: LDS-free MFMA GEMM per (b,n), row-major inputs ----------------
__global__ __launch_bounds__(256) void xg_k(const unsigned short* __restrict__ hn,
                                            const unsigned short* __restrict__ x1n,
                                            const unsigned short* __restrict__ x2n,
                                            const unsigned short* __restrict__ Wcb,
                                            const float* __restrict__ bc,
                                            unsigned short* __restrict__ xg_bf){
  int tid = threadIdx.x, wv = tid >> 6, ln = tid & 63;
  int p = blockIdx.x*4 + wv;
  int b = p / N_, n = p % N_;
  int g = ln >> 4, r = ln & 15;
  int rr = min(r, 11);
  size_t base = ((size_t)b*N_ + n)*384;
  bf16x8 a0 = *(const bf16x8*)&hn [base + rr*32 + g*8];
  bf16x8 a1 = *(const bf16x8*)&x1n[base + rr*32 + g*8];
  bf16x8 a2 = *(const bf16x8*)&x2n[base + rr*32 + g*8];
  #pragma unroll
  for (int dt = 0; dt < 4; ++dt){
    f32x4 acc = {0.f,0.f,0.f,0.f};
    bf16x8 b0 = *(const bf16x8*)&Wcb[((0*4+g)*64 + dt*16 + r)*8];
    bf16x8 b1 = *(const bf16x8*)&Wcb[((1*4+g)*64 + dt*16 + r)*8];
    bf16x8 b2 = *(const bf16x8*)&Wcb[((2*4+g)*64 + dt*16 + r)*8];
    acc = __builtin_amdgcn_mfma_f32_16x16x32_bf16(a0, b0, acc, 0,0,0);
    acc = __builtin_amdgcn_mfma_f32_16x16x32_bf16(a1, b1, acc, 0,0,0);
    acc = __builtin_amdgcn_mfma_f32_16x16x32_bf16(a2, b2, acc, 0,0,0);
    float bias = bc[dt*16 + r];
    if (g < 3){
      #pragma unroll
      for (int rg = 0; rg < 4; ++rg){
        int t = g*4 + rg;
        xg_bf[(((size_t)b*T_ + t)*N_ + n)*64 + dt*16 + r] = cvt1(acc[rg] + bias);
      }
    }
  }
}

// ---------------- qkv v2 (unchanged) ----------------
__global__ __launch_bounds__(256) void qkv_k(const unsigned short* __restrict__ xg_bf,
                                             const unsigned short* __restrict__ Wallb,
                                             float* __restrict__ qkv48,
                                             unsigned short* __restrict__ Qg,
                                             unsigned short* __restrict__ Kg,
                                             unsigned short* __restrict__ Vg){
  int tid = threadIdx.x, wv = tid >> 6, ln = tid & 63;
  int bt = blockIdx.x / 6;
  int nt = (blockIdx.x % 6)*4 + wv;
  if (nt >= 21) return;
  int g = ln >> 4, r = ln & 15;
  int n0 = nt*16;
  int nc = min(n0 + r, N_-1);
  const unsigned short* arow = xg_bf + ((size_t)bt*N_ + nc)*64;
  bf16x8 a0 = *(const bf16x8*)&arow[g*8];
  bf16x8 a1 = *(const bf16x8*)&arow[32 + g*8];
  const float kscale = 0.35355339059327373f * 1.4426950408889634f;
  int hh = r >> 3, dd = r & 7;
  #pragma unroll
  for (int jt = 0; jt < 9; ++jt){
    f32x4 acc = {0.f,0.f,0.f,0.f};
    bf16x8 b0 = *(const bf16x8*)&Wallb[((0*4+g)*144 + jt*16 + r)*8];
    bf16x8 b1 = *(const bf16x8*)&Wallb[((1*4+g)*144 + jt*16 + r)*8];
    acc = __builtin_amdgcn_mfma_f32_16x16x32_bf16(a0, b0, acc, 0,0,0);
    acc = __builtin_amdgcn_mfma_f32_16x16x32_bf16(a1, b1, acc, 0,0,0);
    #pragma unroll
    for (int rg = 0; rg < 4; ++rg){
      int n = n0 + g*4 + rg;
      if (n >= N_) continue;
      float v = acc[rg];
      if (jt < 3){
        qkv48[((size_t)bt*N_ + n)*48 + jt*16 + r] = v;
      } else if (jt < 5){
        int h = (jt-3)*2 + hh;
        Qg[(((size_t)bt*4 + h)*N_ + n)*8 + dd] = cvt1(v);
      } else if (jt < 7){
        int h = (jt-5)*2 + hh;
        Kg[(((size_t)bt*4 + h)*352 + n)*8 + dd] = cvt1(v * kscale);
      } else {
        int h = (jt-7)*2 + hh;
        int m = n & 31, ks = n >> 5;
        int p32 = (((m & 15) >> 2) << 3) | (m & 3) | ((m & 16) >> 2);
        Vg[(((size_t)bt*4 + h)*11 + ks)*512 + dd*32 + p32] = cvt1(v);
      }
    }
  }
}

// ---------------- fused attention: blocks [0,4032) = gattn v7, [4032,5332) = tattn ----------------
__global__ __launch_bounds__(256) void attn_fused(const float* __restrict__ qkv48,
                                                  const unsigned short* __restrict__ Qg,
                                                  const unsigned short* __restrict__ Kg,
                                                  const unsigned short* __restrict__ Vg,
                                                  const unsigned* __restrict__ bm,
                                                  float* __restrict__ att){
  __shared__ __align__(16) char smem[17408];
  int bid = blockIdx.x;
  int tid = threadIdx.x, wv = tid >> 6, ln = tid & 63;
  if (bid < 4032){
    int bt = (bid & 7)*24 + (bid >> 3)/21;
    int blkin = (bid >> 3) % 21;
    int unit = blkin*4 + wv;
    int h = unit / 21, tile = unit % 21;
    int g = ln >> 4, r = ln & 15, g4 = g*4;
    bool gzero = (g == 0);
    const bf16x8 z8 = {0,0,0,0,0,0,0,0};
    size_t hb = (size_t)bt*4 + h;
    int qb = tile*16;
    int qc = min(qb + r, N_-1);
    const uint4* bmp = (const uint4*)(bm + (size_t)(qb + r)*MW);
    uint4 m0 = bmp[0], m1 = bmp[1], m2 = bmp[2];
    unsigned bmw[11] = {m0.x,m0.y,m0.z,m0.w, m1.x,m1.y,m1.z,m1.w, m2.x,m2.y,m2.z};
    bf16x8 aq = z8;
    if (gzero) aq = *(const bf16x8*)&Qg[(hb*N_ + qc)*8];
    const unsigned short* Kh = Kg + hb*352*8;
    const unsigned short* Vh = Vg + hb*11*512;
    float ssum = 0.f;
    f32x4 acc = {0.f,0.f,0.f,0.f};
    #pragma unroll
    for (int ks = 0; ks < 11; ++ks){
      bf16x8 akA = z8, akB = z8;
      if (gzero){
        akA = *(const bf16x8*)&Kh[(ks*32 + r)*8];
        akB = *(const bf16x8*)&Kh[(ks*32 + 16 + r)*8];
      }
      f32x4 dA = {0.f,0.f,0.f,0.f}, dB = {0.f,0.f,0.f,0.f};
      dA = __builtin_amdgcn_mfma_f32_16x16x32_bf16(akA, aq, dA, 0,0,0);
      dB = __builtin_amdgcn_mfma_f32_16x16x32_bf16(akB, aq, dB, 0,0,0);
      unsigned wm = bmw[ks];
      unsigned bA = (wm >> g4) & 0xFu;
      unsigned bB = (wm >> (g4 + 16)) & 0xFu;
      float pA[4], pB[4];
      #pragma unroll
      for (int rg = 0; rg < 4; ++rg){
        float eA = exp2f(dA[rg]);
        float eB = exp2f(dB[rg]);
        eA = (bA & (1u << rg)) ? 0.f : eA;
        eB = (bB & (1u << rg)) ? 0.f : eB;
        ssum += eA; ssum += eB;
        pA[rg] = eA; pB[rg] = eB;
      }
      uint4 pw = { cvt2(pA[0],pA[1]), cvt2(pA[2],pA[3]),
                   cvt2(pB[0],pB[1]), cvt2(pB[2],pB[3]) };
      bf16x8 avv = *(const bf16x8*)&Vh[ks*512 + r*32 + g*8];
      acc = __builtin_amdgcn_mfma_f32_16x16x32_bf16(avv, u2b(pw), acc, 0,0,0);
    }
    ssum += __shfl_xor(ssum, 16);
    ssum += __shfl_xor(ssum, 32);
    float inv = (ssum > 0.f) ? __builtin_amdgcn_rcpf(ssum) : 0.f;
    int qq = qb + r;
    if (g < 2 && qq < N_){
      float4 o = make_float4(acc[0]*inv, acc[1]*inv, acc[2]*inv, acc[3]*inv);
      *(float4*)(att + ((size_t)bt*N_ + qq)*48 + 16 + h*8 + g4) = o;
    }
  } else {
    int p = (bid - 4032)*4 + wv;
    int b = p / N_, n = p % N_;
    float* qs = (float*)smem + (size_t)wv*576;
    float* ss = (float*)(smem + 9216) + (size_t)wv*288;
    for (int idx = ln; idx < T_*48; idx += 64){
      int t = idx / 48, j = idx % 48;
      qs[idx] = qkv48[(((size_t)b*T_ + t)*N_ + n)*48 + j];
    }
    const float scale = 0.35355339059327373f;
    for (int idx = ln; idx < 2*T_*T_; idx += 64){
      int hh = idx / 144, r2 = (idx / T_) % T_, c = idx % T_;
      float acc = 0.f;
      for (int d = 0; d < 8; ++d) acc += qs[r2*48 + hh*8 + d] * qs[c*48 + 16 + hh*8 + d];
      ss[idx] = acc * scale;
    }
    if (ln < 2*T_){
      int hh = ln / T_, r2 = ln % T_;
      float* row = ss + hh*144 + r2*T_;
      float m = -INFINITY; for (int k = 0; k < T_; ++k) m = fmaxf(m, row[k]);
      float s = 0.f; for (int k = 0; k < T_; ++k){ float e = __expf(row[k] - m); row[k] = e; s += e; }
      float inv = 1.f / s; for (int k = 0; k < T_; ++k) row[k] *= inv;
    }
    for (int idx = ln; idx < T_*16; idx += 64){
      int t = idx / 16, o = idx % 16; int hh = o / 8, d = o % 8;
      float acc = 0.f;
      const float* row = ss + hh*144 + t*T_;
      for (int k = 0; k < T_; ++k) acc += row[k] * qs[k*48 + 32 + hh*8 + d];
      att[(((size_t)b*T_ + t)*N_ + n)*48 + o] = acc;
    }
  }
}

// ---------------- final projection: MFMA GEMM (unchanged) ----------------
__global__ __launch_bounds__(256) void proj_k(const float* __restrict__ att,
                                              const unsigned short* __restrict__ Wpb,
                                              const float* __restrict__ b_proj,
                                              float* __restrict__ out){
  int tid = threadIdx.x, wv = tid >> 6, ln = tid & 63;
  int g = ln >> 4, r = ln & 15;
  long r0 = ((long)blockIdx.x*4 + wv)*16;
  const float* arow = att + (r0 + r)*48;
  float4 qa = *(const float4*)&arow[g*8];
  float4 qb = *(const float4*)&arow[g*8 + 4];
  uint4 u0 = { cvt2(qa.x,qa.y), cvt2(qa.z,qa.w), cvt2(qb.x,qb.y), cvt2(qb.z,qb.w) };
  bf16x8 a0 = u2b(u0);
  bf16x8 a1 = {0,0,0,0,0,0,0,0};
  if (g < 2){
    float4 qc = *(const float4*)&arow[32 + g*8];
    float4 qd = *(const float4*)&arow[36 + g*8];
    uint4 u1 = { cvt2(qc.x,qc.y), cvt2(qc.z,qc.w), cvt2(qd.x,qd.y), cvt2(qd.z,qd.w) };
    a1 = u2b(u1);
  }
  #pragma unroll
  for (int dt = 0; dt < 4; ++dt){
    f32x4 acc = {0.f,0.f,0.f,0.f};
    bf16x8 b0 = *(const bf16x8*)&Wpb[((0*4+g)*64 + dt*16 + r)*8];
    bf16x8 b1 = *(const bf16x8*)&Wpb[((1*4+g)*64 + dt*16 + r)*8];
    acc = __builtin_amdgcn_mfma_f32_16x16x32_bf16(a0, b0, acc, 0,0,0);
    acc = __builtin_amdgcn_mfma_f32_16x16x32_bf16(a1, b1, acc, 0,0,0);
    float bias = b_proj[dt*16 + r];
    #pragma unroll
    for (int rg = 0; rg < 4; ++rg)
      out[(r0 + g*4 + rg)*64 + dt*16 + r] = acc[rg] + bias;
  }
}

extern "C" void kernel_launch(void* const* d_in, const int* in_sizes, int n_in,
                              void* d_out, int out_size, void* d_ws, size_t ws_size,
                              hipStream_t stream){
  const float* x      = (const float*)d_in[0];
  const int*   ind    = (const int*)  d_in[1];
  const unsigned char* gmask_raw = (const unsigned char*)d_in[4];
  const float* p1     = (const float*)d_in[5];
  const float* p2     = (const float*)d_in[6];
  const float* p3     = (const float*)d_in[7];
  const float* pk     = (const float*)d_in[8];
  const float* W_r1   = (const float*)d_in[9];
  const float* b_r1   = (const float*)d_in[10];
  const float* W_gcn  = (const float*)d_in[11];
  const float* b_gcn  = (const float*)d_in[12];
  const float* W_r2   = (const float*)d_in[13];
  const float* b_r2   = (const float*)d_in[14];
  const float* Wtq    = (const float*)d_in[15];
  const float* Wtk    = (const float*)d_in[16];
  const float* Wtv    = (const float*)d_in[17];
  const float* Wgq    = (const float*)d_in[18];
  const float* Wgk    = (const float*)d_in[19];
  const float* Wgv    = (const float*)d_in[20];
  const float* W_proj = (const float*)d_in[21];
  const float* b_proj = (const float*)d_in[22];
  float* out = (float*)d_out;

  float* ws = (float*)d_ws;
  float* A1    = ws; ws += B_*DIMS_*DIMS_;
  float* bc    = ws; ws += 64;
  float* p3t   = ws; ws += DIMS_*N_;
  float* qkv48 = ws; ws += (size_t)B_*T_*N_*48;
  float* att   = ws; ws += (size_t)B_*T_*N_*48;
  unsigned* bm = (unsigned*)ws; ws += NQP*MW;
  unsigned short* us = (unsigned short*)ws;
  unsigned short* adp_bf = us; us += (size_t)B_*N_*VP;
  unsigned short* ht     = us; us += (size_t)B_*384*VP;
  unsigned short* x1t    = us; us += (size_t)B_*384*VP;
  unsigned short* hn     = us; us += (size_t)B_*N_*384;
  unsigned short* x1n    = us; us += (size_t)B_*N_*384;
  unsigned short* x2n    = us; us += (size_t)B_*N_*384;
  unsigned short* xg_bf  = us; us += (size_t)B_*T_*N_*64;
  unsigned short* Qg     = us; us += (size_t)192*4*N_*8;
  unsigned short* Kg     = us; us += (size_t)192*4*352*8;
  unsigned short* Vg     = us; us += (size_t)192*4*11*512;
  unsigned short* Wcb    = us; us += 3*4*64*8;
  unsigned short* Wallb  = us; us += 2*4*144*8;
  unsigned short* Wpb    = us; us += 2*4*64*8;

  setup_k     <<<36,        256, 0, stream>>>(p1, pk, ind, A1, gmask_raw, bm, p3, p3t,
                                              W_gcn, b_gcn, W_r2, b_r2,
                                              Wtq, Wtk, Wtv, Wgq, Wgk, Wgv,
                                              W_proj, bc, Wcb, Wallb, Wpb);
  mid_k       <<<1152+1300, 256, 0, stream>>>(x, W_r1, b_r1, ht, hn, p2, p3t, A1, adp_bf);
  gcn_mfma    <<<B_*36,     256, 0, stream>>>(adp_bf, ht,  x1t, x1n);
  gcn_mfma    <<<B_*36,     256, 0, stream>>>(adp_bf, x1t, (unsigned short*)nullptr, x2n);
  xg_k        <<<(B_*N_)/4, 256, 0, stream>>>(hn, x1n, x2n, Wcb, bc, xg_bf);
  qkv_k       <<<192*6,     256, 0, stream>>>(xg_bf, Wallb, qkv48, Qg, Kg, Vg);
  attn_fused  <<<4032+1300, 256, 0, stream>>>(qkv48, Qg, Kg, Vg, bm, att);
  proj_k      <<<(B_*T_*N_/16)/4, 256, 0, stream>>>(att, Wpb, b_proj, out);
}

// Round 16
// 168.039 us; speedup vs baseline: 1.0840x; 1.0840x over previous
//
#include <hip/hip_runtime.h>
#include <hip/hip_bf16.h>
#include <math.h>

#define B_ 16
#define T_ 12
#define N_ 325
#define DIMS_ 40
#define DAYS_ 288
#define MW 12          // bitmask words per mask row (11 used, 1 pad)
#define NQP 336        // padded q-rows for mask (21*16)
#define VP 352         // padded v/ct-row stride for transposed bf16 arrays (11*32)

typedef __attribute__((ext_vector_type(8))) short bf16x8;
typedef __attribute__((ext_vector_type(4))) float f32x4;

__device__ __forceinline__ unsigned short cvt1(float f){
  unsigned w;
  asm("v_cvt_pk_bf16_f32 %0, %1, %2" : "=v"(w) : "v"(f), "v"(f));
  return (unsigned short)w;
}
__device__ __forceinline__ unsigned cvt2(float a, float b){
  unsigned w;
  asm("v_cvt_pk_bf16_f32 %0, %1, %2" : "=v"(w) : "v"(a), "v"(b));
  return w;
}
__device__ __forceinline__ bf16x8 u2b(uint4 u){ return __builtin_bit_cast(bf16x8, u); }

// ---------------- fused setup + hproj ----------------
// blocks 0-15: dg_a1 | 16-31: mask_bits (inline dtype detect) | 32: p3 transpose
// blocks 33-35: weight prep (Wc/bc/Wcb, Wallb, Wpb) | blocks 36..1187: hproj MFMA
__global__ __launch_bounds__(256) void setup_hproj_k(
                        const float* __restrict__ p1, const float* __restrict__ pk,
                        const int* __restrict__ ind, float* __restrict__ A1,
                        const unsigned char* __restrict__ raw, unsigned* __restrict__ bm,
                        const float* __restrict__ p3, float* __restrict__ p3t,
                        const float* W_gcn, const float* b_gcn, const float* W_r2, const float* b_r2,
                        const float* Wtq, const float* Wtk, const float* Wtv,
                        const float* Wgq, const float* Wgk, const float* Wgv,
                        const float* W_proj,
                        float* bc, unsigned short* Wcb, unsigned short* Wallb,
                        unsigned short* Wpb,
                        const float* __restrict__ x, const float* __restrict__ W_r1,
                        const float* __restrict__ b_r1,
                        unsigned short* __restrict__ ht, unsigned short* __restrict__ hn){
  int tid = threadIdx.x;
  if (blockIdx.x >= 36){
    // ---- hproj MFMA, W_r1 read directly (RNE cvt identical to prep path) ----
    int bid = blockIdx.x - 36;
    int wv = tid >> 6, ln = tid & 63;
    int bt = bid / 6;
    int nt = (bid % 6)*4 + wv;
    if (nt >= 21) return;
    int g = ln >> 4, r = ln & 15;
    int n0 = nt*16;
    int nc = min(n0 + r, N_-1);
    int b = bt / T_, t = bt % T_;
    const float* xrow = x + ((size_t)bt*N_ + nc)*64;
    float4 xa = *(const float4*)&xrow[g*8];
    float4 xb = *(const float4*)&xrow[g*8 + 4];
    uint4 u0 = { cvt2(xa.x,xa.y), cvt2(xa.z,xa.w), cvt2(xb.x,xb.y), cvt2(xb.z,xb.w) };
    bf16x8 bv0 = u2b(u0);
    float4 xc = *(const float4*)&xrow[32 + g*8];
    float4 xd = *(const float4*)&xrow[32 + g*8 + 4];
    uint4 u1 = { cvt2(xc.x,xc.y), cvt2(xc.z,xc.w), cvt2(xd.x,xd.y), cvt2(xd.z,xd.w) };
    bf16x8 bv1 = u2b(u1);
    int n = n0 + r;
    #pragma unroll
    for (int ct = 0; ct < 2; ++ct){
      const float* wrow = W_r1 + (ct*16 + r)*64;
      float4 wa = *(const float4*)&wrow[g*8];
      float4 wb = *(const float4*)&wrow[g*8 + 4];
      uint4 ua = { cvt2(wa.x,wa.y), cvt2(wa.z,wa.w), cvt2(wb.x,wb.y), cvt2(wb.z,wb.w) };
      bf16x8 a0 = u2b(ua);
      float4 wc = *(const float4*)&wrow[32 + g*8];
      float4 wd = *(const float4*)&wrow[32 + g*8 + 4];
      uint4 ub = { cvt2(wc.x,wc.y), cvt2(wc.z,wc.w), cvt2(wd.x,wd.y), cvt2(wd.z,wd.w) };
      bf16x8 a1 = u2b(ub);
      f32x4 acc = {0.f,0.f,0.f,0.f};
      acc = __builtin_amdgcn_mfma_f32_16x16x32_bf16(a0, bv0, acc, 0,0,0);
      acc = __builtin_amdgcn_mfma_f32_16x16x32_bf16(a1, bv1, acc, 0,0,0);
      if (n < N_){
        float v0 = acc[0] + b_r1[ct*16 + g*4 + 0];
        float v1 = acc[1] + b_r1[ct*16 + g*4 + 1];
        float v2 = acc[2] + b_r1[ct*16 + g*4 + 2];
        float v3 = acc[3] + b_r1[ct*16 + g*4 + 3];
        int c0 = ct*16 + g*4;
        ht[((size_t)b*384 + t*32 + c0+0)*VP + n] = cvt1(v0);
        ht[((size_t)b*384 + t*32 + c0+1)*VP + n] = cvt1(v1);
        ht[((size_t)b*384 + t*32 + c0+2)*VP + n] = cvt1(v2);
        ht[((size_t)b*384 + t*32 + c0+3)*VP + n] = cvt1(v3);
        uint2 hp = { cvt2(v0, v1), cvt2(v2, v3) };
        *(uint2*)&hn[((size_t)b*N_ + n)*384 + t*32 + c0] = hp;
      }
    }
    return;
  }
  if (blockIdx.x < 16){
    int b = blockIdx.x;
    __shared__ float te[DIMS_];
    int day = ind[b] % DAYS_; if (day < 0) day += DAYS_;
    for (int i = tid; i < DIMS_; i += blockDim.x) te[i] = p1[day*DIMS_ + i];
    __syncthreads();
    for (int jk = tid; jk < DIMS_*DIMS_; jk += blockDim.x){
      float acc = 0.f;
      for (int i = 0; i < DIMS_; ++i) acc += te[i] * pk[i*DIMS_*DIMS_ + jk];
      A1[b*DIMS_*DIMS_ + jk] = acc;
    }
  } else if (blockIdx.x < 32){
    __shared__ int f1, f3, fo;
    if (tid == 0){ f1 = 0; f3 = 0; fo = 0; }
    __syncthreads();
    for (int i = tid; i < 4096; i += 256){
      unsigned char v = raw[i];
      int m4 = i & 3;
      if (v == 0x3F && m4 == 1) atomicOr(&f1, 1);
      if (v == 0x3F && m4 == 3) atomicOr(&f3, 1);
      if (v != 0 && m4 != 0)    atomicOr(&fo, 1);
    }
    __syncthreads();
    int mode = f1 ? 2 : (f3 ? 3 : (fo ? 0 : 1));
    int idx = (blockIdx.x - 16) * 256 + tid;
    if (idx >= NQP * MW) return;
    int q = idx / MW, w = idx % MW;
    if (q >= N_) { bm[idx] = 0xFFFFFFFFu; return; }
    unsigned bits = 0;
    for (int j = 0; j < 32; ++j){
      int k = w*32 + j;
      int v;
      if (k >= N_) v = 1;
      else {
        size_t i = (size_t)q*N_ + k;
        if (mode == 0)      v = raw[i] != 0;
        else if (mode == 1) v = ((const int*)raw)[i] != 0;
        else if (mode == 2) { unsigned short u = ((const unsigned short*)raw)[i]; v = (u & 0x7FFF) != 0; }
        else                { float f = ((const float*)raw)[i]; v = (f != 0.f); }
      }
      bits |= (unsigned)v << j;
    }
    bm[idx] = bits;
  } else if (blockIdx.x == 32){
    for (int idx = tid; idx < DIMS_*N_; idx += 256){
      int k = idx / N_, c = idx % N_;
      p3t[idx] = p3[c*DIMS_ + k];
    }
  } else if (blockIdx.x == 33){
    __shared__ float WcS[64*96];
    for (int idx = tid; idx < 64*96; idx += 256){
      int d = idx / 96, c = idx % 96;
      float acc = 0.f;
      for (int o = 0; o < 32; ++o) acc += W_r2[d*32 + o] * W_gcn[o*96 + c];
      WcS[idx] = acc;
    }
    for (int d = tid; d < 64; d += 256){
      float acc = b_r2[d];
      for (int o = 0; o < 32; ++o) acc += W_r2[d*32 + o] * b_gcn[o];
      bc[d] = acc;
    }
    __syncthreads();
    for (int idx = tid; idx < 3*4*64*8; idx += 256){
      int jj = idx & 7, rest = idx >> 3;
      int d = rest % 64, gk = rest / 64;
      int g = gk & 3, kc = gk >> 2;
      Wcb[idx] = cvt1(WcS[d*96 + kc*32 + g*8 + jj]);
    }
  } else if (blockIdx.x == 34){
    for (int idx = tid; idx < 2*4*144*8; idx += 256){
      int jj = idx & 7, rest = idx >> 3;
      int j = rest % 144, gk = rest / 144;
      int g = gk & 3, kc = gk >> 2;
      int dd = kc*32 + g*8 + jj;
      const float* src; int rsrc;
      if      (j < 16) { src = Wtq; rsrc = j; }
      else if (j < 32) { src = Wtk; rsrc = j - 16; }
      else if (j < 48) { src = Wtv; rsrc = j - 32; }
      else if (j < 80) { src = Wgq; rsrc = j - 48; }
      else if (j < 112){ src = Wgk; rsrc = j - 80; }
      else             { src = Wgv; rsrc = j - 112; }
      Wallb[idx] = cvt1(src[rsrc*64 + dd]);
    }
  } else {
    for (int idx = tid; idx < 2*4*64*8; idx += 256){
      int jj = idx & 7, rest = idx >> 3;
      int d = rest % 64, gk = rest / 64;
      int g = gk & 3, kc = gk >> 2;
      int k = kc*32 + g*8 + jj;
      Wpb[idx] = (k < 48) ? cvt1(W_proj[d*48 + k]) : (unsigned short)0;
    }
  }
}

// ---------------- dg_adp: round-14 block version (128 threads) ----------------
__global__ void dg_adp(const float* __restrict__ p2, const float* __restrict__ p3t,
                       const float* __restrict__ A1, unsigned short* __restrict__ adp_bf){
  int bid = blockIdx.x; int b = bid / N_; int n = bid % N_;
  __shared__ float p2r[DIMS_], t2[DIMS_], sbuf[N_], red[128];
  int tid = threadIdx.x;
  if (tid < DIMS_) p2r[tid] = p2[n*DIMS_ + tid];
  __syncthreads();
  if (tid < DIMS_){
    float acc = 0.f;
    const float* a1 = A1 + b*DIMS_*DIMS_;
    for (int j = 0; j < DIMS_; ++j) acc += p2r[j] * a1[j*DIMS_ + tid];
    t2[tid] = acc;
  }
  __syncthreads();
  float lm = -INFINITY;
  for (int c = tid; c < N_; c += 128){
    float acc = 0.f;
    for (int k = 0; k < DIMS_; ++k) acc += p3t[k*N_ + c] * t2[k];
    acc = fmaxf(acc, 0.f);
    sbuf[c] = acc; lm = fmaxf(lm, acc);
  }
  red[tid] = lm; __syncthreads();
  for (int off = 64; off; off >>= 1){ if (tid < off) red[tid] = fmaxf(red[tid], red[tid+off]); __syncthreads(); }
  float m = red[0]; __syncthreads();
  float ls = 0.f;
  for (int c = tid; c < N_; c += 128){ float e = __expf(sbuf[c] - m); sbuf[c] = e; ls += e; }
  red[tid] = ls; __syncthreads();
  for (int off = 64; off; off >>= 1){ if (tid < off) red[tid] += red[tid+off]; __syncthreads(); }
  float inv = 1.f / red[0];
  unsigned short* outp = adp_bf + ((size_t)b*N_ + n) * VP;
  for (int c = tid; c < VP; c += 128)
    outp[c] = (c < N_) ? cvt1(sbuf[c] * inv) : (unsigned short)0;
}

// ---------------- GCN hop as MFMA GEMM; out_t (transposed, nullable) + out_n (row-major) ----------------
__global__ __launch_bounds__(256) void gcn_mfma(const unsigned short* __restrict__ adp_bf,
                                                const unsigned short* __restrict__ in_t,
                                                unsigned short* __restrict__ out_t,
                                                unsigned short* __restrict__ out_n){
  int bi = blockIdx.x;
  int b = bi / 36, rest = bi % 36;
  int wt = rest / 6, ctb = rest % 6;
  int tid = threadIdx.x, wv = tid >> 6, ln = tid & 63, g = ln >> 4, r = ln & 15;
  int w0 = wt*64 + wv*16;
  int ct0 = ctb*64;
  int wr = min(w0 + r, N_-1);
  const unsigned short* arow  = adp_bf + ((size_t)b*N_ + wr)*VP;
  const unsigned short* bbase = in_t  + ((size_t)b*384 + ct0)*VP;
  f32x4 acc0={0.f,0.f,0.f,0.f}, acc1=acc0, acc2=acc0, acc3=acc0;
  #pragma unroll
  for (int ks = 0; ks < 11; ++ks){
    int ko = ks*32 + g*8;
    bf16x8 a  = *(const bf16x8*)&arow[ko];
    bf16x8 b0 = *(const bf16x8*)&bbase[(size_t)( 0 + r)*VP + ko];
    bf16x8 b1 = *(const bf16x8*)&bbase[(size_t)(16 + r)*VP + ko];
    bf16x8 b2 = *(const bf16x8*)&bbase[(size_t)(32 + r)*VP + ko];
    bf16x8 b3 = *(const bf16x8*)&bbase[(size_t)(48 + r)*VP + ko];
    acc0 = __builtin_amdgcn_mfma_f32_16x16x32_bf16(a, b0, acc0, 0,0,0);
    acc1 = __builtin_amdgcn_mfma_f32_16x16x32_bf16(a, b1, acc1, 0,0,0);
    acc2 = __builtin_amdgcn_mfma_f32_16x16x32_bf16(a, b2, acc2, 0,0,0);
    acc3 = __builtin_amdgcn_mfma_f32_16x16x32_bf16(a, b3, acc3, 0,0,0);
  }
  f32x4 av[4] = {acc0, acc1, acc2, acc3};
  if (out_t && w0 + 15 < VP){
    #pragma unroll
    for (int dt = 0; dt < 4; ++dt){
      int ct = ct0 + dt*16 + r;
      uint2 pk2 = { cvt2(av[dt][0], av[dt][1]), cvt2(av[dt][2], av[dt][3]) };
      *(uint2*)&out_t[((size_t)b*384 + ct)*VP + w0 + g*4] = pk2;
    }
  }
  #pragma unroll
  for (int dt = 0; dt < 4; ++dt){
    int ct = ct0 + dt*16 + r;
    #pragma unroll
    for (int rg = 0; rg < 4; ++rg){
      int w = w0 + g*4 + rg;
      if (w < N_) out_n[((size_t)b*N_ + w)*384 + ct] = cvt1(av[dt][rg]);
    }
  }
}

// ---------------- xg: LDS-free MFMA GEMM per (b,n), row-major inputs ----------------
__global__ __launch_bounds__(256) void xg_k(const unsigned short* __restrict__ hn,
                                            const unsigned short* __restrict__ x1n,
                                            const unsigned short* __restrict__ x2n,
                                            const unsigned short* __restrict__ Wcb,
                                            const float* __restrict__ bc,
                                            unsigned short* __restrict__ xg_bf){
  int tid = threadIdx.x, wv = tid >> 6, ln = tid & 63;
  int p = blockIdx.x*4 + wv;
  int b = p / N_, n = p % N_;
  int g = ln >> 4, r = ln & 15;
  int rr = min(r, 11);
  size_t base = ((size_t)b*N_ + n)*384;
  bf16x8 a0 = *(const bf16x8*)&hn [base + rr*32 + g*8];
  bf16x8 a1 = *(const bf16x8*)&x1n[base + rr*32 + g*8];
  bf16x8 a2 = *(const bf16x8*)&x2n[base + rr*32 + g*8];
  #pragma unroll
  for (int dt = 0; dt < 4; ++dt){
    f32x4 acc = {0.f,0.f,0.f,0.f};
    bf16x8 b0 = *(const bf16x8*)&Wcb[((0*4+g)*64 + dt*16 + r)*8];
    bf16x8 b1 = *(const bf16x8*)&Wcb[((1*4+g)*64 + dt*16 + r)*8];
    bf16x8 b2 = *(const bf16x8*)&Wcb[((2*4+g)*64 + dt*16 + r)*8];
    acc = __builtin_amdgcn_mfma_f32_16x16x32_bf16(a0, b0, acc, 0,0,0);
    acc = __builtin_amdgcn_mfma_f32_16x16x32_bf16(a1, b1, acc, 0,0,0);
    acc = __builtin_amdgcn_mfma_f32_16x16x32_bf16(a2, b2, acc, 0,0,0);
    float bias = bc[dt*16 + r];
    if (g < 3){
      #pragma unroll
      for (int rg = 0; rg < 4; ++rg){
        int t = g*4 + rg;
        xg_bf[(((size_t)b*T_ + t)*N_ + n)*64 + dt*16 + r] = cvt1(acc[rg] + bias);
      }
    }
  }
}

// ---------------- qkv v2 (unchanged) ----------------
__global__ __launch_bounds__(256) void qkv_k(const unsigned short* __restrict__ xg_bf,
                                             const unsigned short* __restrict__ Wallb,
                                             float* __restrict__ qkv48,
                                             unsigned short* __restrict__ Qg,
                                             unsigned short* __restrict__ Kg,
                                             unsigned short* __restrict__ Vg){
  int tid = threadIdx.x, wv = tid >> 6, ln = tid & 63;
  int bt = blockIdx.x / 6;
  int nt = (blockIdx.x % 6)*4 + wv;
  if (nt >= 21) return;
  int g = ln >> 4, r = ln & 15;
  int n0 = nt*16;
  int nc = min(n0 + r, N_-1);
  const unsigned short* arow = xg_bf + ((size_t)bt*N_ + nc)*64;
  bf16x8 a0 = *(const bf16x8*)&arow[g*8];
  bf16x8 a1 = *(const bf16x8*)&arow[32 + g*8];
  const float kscale = 0.35355339059327373f * 1.4426950408889634f;
  int hh = r >> 3, dd = r & 7;
  #pragma unroll
  for (int jt = 0; jt < 9; ++jt){
    f32x4 acc = {0.f,0.f,0.f,0.f};
    bf16x8 b0 = *(const bf16x8*)&Wallb[((0*4+g)*144 + jt*16 + r)*8];
    bf16x8 b1 = *(const bf16x8*)&Wallb[((1*4+g)*144 + jt*16 + r)*8];
    acc = __builtin_amdgcn_mfma_f32_16x16x32_bf16(a0, b0, acc, 0,0,0);
    acc = __builtin_amdgcn_mfma_f32_16x16x32_bf16(a1, b1, acc, 0,0,0);
    #pragma unroll
    for (int rg = 0; rg < 4; ++rg){
      int n = n0 + g*4 + rg;
      if (n >= N_) continue;
      float v = acc[rg];
      if (jt < 3){
        qkv48[((size_t)bt*N_ + n)*48 + jt*16 + r] = v;
      } else if (jt < 5){
        int h = (jt-3)*2 + hh;
        Qg[(((size_t)bt*4 + h)*N_ + n)*8 + dd] = cvt1(v);
      } else if (jt < 7){
        int h = (jt-5)*2 + hh;
        Kg[(((size_t)bt*4 + h)*352 + n)*8 + dd] = cvt1(v * kscale);
      } else {
        int h = (jt-7)*2 + hh;
        int m = n & 31, ks = n >> 5;
        int p32 = (((m & 15) >> 2) << 3) | (m & 3) | ((m & 16) >> 2);
        Vg[(((size_t)bt*4 + h)*11 + ks)*512 + dd*32 + p32] = cvt1(v);
      }
    }
  }
}

// ---------------- fused attention: blocks [0,4032) = gattn v7, [4032,5332) = tattn ----------------
__global__ __launch_bounds__(256) void attn_fused(const float* __restrict__ qkv48,
                                                  const unsigned short* __restrict__ Qg,
                                                  const unsigned short* __restrict__ Kg,
                                                  const unsigned short* __restrict__ Vg,
                                                  const unsigned* __restrict__ bm,
                                                  float* __restrict__ att){
  __shared__ __align__(16) char smem[17408];
  int bid = blockIdx.x;
  int tid = threadIdx.x, wv = tid >> 6, ln = tid & 63;
  if (bid < 4032){
    int bt = (bid & 7)*24 + (bid >> 3)/21;
    int blkin = (bid >> 3) % 21;
    int unit = blkin*4 + wv;
    int h = unit / 21, tile = unit % 21;
    int g = ln >> 4, r = ln & 15, g4 = g*4;
    bool gzero = (g == 0);
    const bf16x8 z8 = {0,0,0,0,0,0,0,0};
    size_t hb = (size_t)bt*4 + h;
    int qb = tile*16;
    int qc = min(qb + r, N_-1);
    const uint4* bmp = (const uint4*)(bm + (size_t)(qb + r)*MW);
    uint4 m0 = bmp[0], m1 = bmp[1], m2 = bmp[2];
    unsigned bmw[11] = {m0.x,m0.y,m0.z,m0.w, m1.x,m1.y,m1.z,m1.w, m2.x,m2.y,m2.z};
    bf16x8 aq = z8;
    if (gzero) aq = *(const bf16x8*)&Qg[(hb*N_ + qc)*8];
    const unsigned short* Kh = Kg + hb*352*8;
    const unsigned short* Vh = Vg + hb*11*512;
    float ssum = 0.f;
    f32x4 acc = {0.f,0.f,0.f,0.f};
    #pragma unroll
    for (int ks = 0; ks < 11; ++ks){
      bf16x8 akA = z8, akB = z8;
      if (gzero){
        akA = *(const bf16x8*)&Kh[(ks*32 + r)*8];
        akB = *(const bf16x8*)&Kh[(ks*32 + 16 + r)*8];
      }
      f32x4 dA = {0.f,0.f,0.f,0.f}, dB = {0.f,0.f,0.f,0.f};
      dA = __builtin_amdgcn_mfma_f32_16x16x32_bf16(akA, aq, dA, 0,0,0);
      dB = __builtin_amdgcn_mfma_f32_16x16x32_bf16(akB, aq, dB, 0,0,0);
      unsigned wm = bmw[ks];
      unsigned bA = (wm >> g4) & 0xFu;
      unsigned bB = (wm >> (g4 + 16)) & 0xFu;
      float pA[4], pB[4];
      #pragma unroll
      for (int rg = 0; rg < 4; ++rg){
        float eA = exp2f(dA[rg]);
        float eB = exp2f(dB[rg]);
        eA = (bA & (1u << rg)) ? 0.f : eA;
        eB = (bB & (1u << rg)) ? 0.f : eB;
        ssum += eA; ssum += eB;
        pA[rg] = eA; pB[rg] = eB;
      }
      uint4 pw = { cvt2(pA[0],pA[1]), cvt2(pA[2],pA[3]),
                   cvt2(pB[0],pB[1]), cvt2(pB[2],pB[3]) };
      bf16x8 avv = *(const bf16x8*)&Vh[ks*512 + r*32 + g*8];
      acc = __builtin_amdgcn_mfma_f32_16x16x32_bf16(avv, u2b(pw), acc, 0,0,0);
    }
    ssum += __shfl_xor(ssum, 16);
    ssum += __shfl_xor(ssum, 32);
    float inv = (ssum > 0.f) ? __builtin_amdgcn_rcpf(ssum) : 0.f;
    int qq = qb + r;
    if (g < 2 && qq < N_){
      float4 o = make_float4(acc[0]*inv, acc[1]*inv, acc[2]*inv, acc[3]*inv);
      *(float4*)(att + ((size_t)bt*N_ + qq)*48 + 16 + h*8 + g4) = o;
    }
  } else {
    int p = (bid - 4032)*4 + wv;
    int b = p / N_, n = p % N_;
    float* qs = (float*)smem + (size_t)wv*576;
    float* ss = (float*)(smem + 9216) + (size_t)wv*288;
    for (int idx = ln; idx < T_*48; idx += 64){
      int t = idx / 48, j = idx % 48;
      qs[idx] = qkv48[(((size_t)b*T_ + t)*N_ + n)*48 + j];
    }
    const float scale = 0.35355339059327373f;
    for (int idx = ln; idx < 2*T_*T_; idx += 64){
      int hh = idx / 144, r2 = (idx / T_) % T_, c = idx % T_;
      float acc = 0.f;
      for (int d = 0; d < 8; ++d) acc += qs[r2*48 + hh*8 + d] * qs[c*48 + 16 + hh*8 + d];
      ss[idx] = acc * scale;
    }
    if (ln < 2*T_){
      int hh = ln / T_, r2 = ln % T_;
      float* row = ss + hh*144 + r2*T_;
      float m = -INFINITY; for (int k = 0; k < T_; ++k) m = fmaxf(m, row[k]);
      float s = 0.f; for (int k = 0; k < T_; ++k){ float e = __expf(row[k] - m); row[k] = e; s += e; }
      float inv = 1.f / s; for (int k = 0; k < T_; ++k) row[k] *= inv;
    }
    for (int idx = ln; idx < T_*16; idx += 64){
      int t = idx / 16, o = idx % 16; int hh = o / 8, d = o % 8;
      float acc = 0.f;
      const float* row = ss + hh*144 + t*T_;
      for (int k = 0; k < T_; ++k) acc += row[k] * qs[k*48 + 32 + hh*8 + d];
      att[(((size_t)b*T_ + t)*N_ + n)*48 + o] = acc;
    }
  }
}

// ---------------- final projection: MFMA GEMM (unchanged) ----------------
__global__ __launch_bounds__(256) void proj_k(const float* __restrict__ att,
                                              const unsigned short* __restrict__ Wpb,
                                              const float* __restrict__ b_proj,
                                              float* __restrict__ out){
  int tid = threadIdx.x, wv = tid >> 6, ln = tid & 63;
  int g = ln >> 4, r = ln & 15;
  long r0 = ((long)blockIdx.x*4 + wv)*16;
  const float* arow = att + (r0 + r)*48;
  float4 qa = *(const float4*)&arow[g*8];
  float4 qb = *(const float4*)&arow[g*8 + 4];
  uint4 u0 = { cvt2(qa.x,qa.y), cvt2(qa.z,qa.w), cvt2(qb.x,qb.y), cvt2(qb.z,qb.w) };
  bf16x8 a0 = u2b(u0);
  bf16x8 a1 = {0,0,0,0,0,0,0,0};
  if (g < 2){
    float4 qc = *(const float4*)&arow[32 + g*8];
    float4 qd = *(const float4*)&arow[36 + g*8];
    uint4 u1 = { cvt2(qc.x,qc.y), cvt2(qc.z,qc.w), cvt2(qd.x,qd.y), cvt2(qd.z,qd.w) };
    a1 = u2b(u1);
  }
  #pragma unroll
  for (int dt = 0; dt < 4; ++dt){
    f32x4 acc = {0.f,0.f,0.f,0.f};
    bf16x8 b0 = *(const bf16x8*)&Wpb[((0*4+g)*64 + dt*16 + r)*8];
    bf16x8 b1 = *(const bf16x8*)&Wpb[((1*4+g)*64 + dt*16 + r)*8];
    acc = __builtin_amdgcn_mfma_f32_16x16x32_bf16(a0, b0, acc, 0,0,0);
    acc = __builtin_amdgcn_mfma_f32_16x16x32_bf16(a1, b1, acc, 0,0,0);
    float bias = b_proj[dt*16 + r];
    #pragma unroll
    for (int rg = 0; rg < 4; ++rg)
      out[(r0 + g*4 + rg)*64 + dt*16 + r] = acc[rg] + bias;
  }
}

extern "C" void kernel_launch(void* const* d_in, const int* in_sizes, int n_in,
                              void* d_out, int out_size, void* d_ws, size_t ws_size,
                              hipStream_t stream){
  const float* x      = (const float*)d_in[0];
  const int*   ind    = (const int*)  d_in[1];
  const unsigned char* gmask_raw = (const unsigned char*)d_in[4];
  const float* p1     = (const float*)d_in[5];
  const float* p2     = (const float*)d_in[6];
  const float* p3     = (const float*)d_in[7];
  const float* pk     = (const float*)d_in[8];
  const float* W_r1   = (const float*)d_in[9];
  const float* b_r1   = (const float*)d_in[10];
  const float* W_gcn  = (const float*)d_in[11];
  const float* b_gcn  = (const float*)d_in[12];
  const float* W_r2   = (const float*)d_in[13];
  const float* b_r2   = (const float*)d_in[14];
  const float* Wtq    = (const float*)d_in[15];
  const float* Wtk    = (const float*)d_in[16];
  const float* Wtv    = (const float*)d_in[17];
  const float* Wgq    = (const float*)d_in[18];
  const float* Wgk    = (const float*)d_in[19];
  const float* Wgv    = (const float*)d_in[20];
  const float* W_proj = (const float*)d_in[21];
  const float* b_proj = (const float*)d_in[22];
  float* out = (float*)d_out;

  float* ws = (float*)d_ws;
  float* A1    = ws; ws += B_*DIMS_*DIMS_;
  float* bc    = ws; ws += 64;
  float* p3t   = ws; ws += DIMS_*N_;
  float* qkv48 = ws; ws += (size_t)B_*T_*N_*48;
  float* att   = ws; ws += (size_t)B_*T_*N_*48;
  unsigned* bm = (unsigned*)ws; ws += NQP*MW;
  unsigned short* us = (unsigned short*)ws;
  unsigned short* adp_bf = us; us += (size_t)B_*N_*VP;
  unsigned short* ht     = us; us += (size_t)B_*384*VP;
  unsigned short* x1t    = us; us += (size_t)B_*384*VP;
  unsigned short* hn     = us; us += (size_t)B_*N_*384;
  unsigned short* x1n    = us; us += (size_t)B_*N_*384;
  unsigned short* x2n    = us; us += (size_t)B_*N_*384;
  unsigned short* xg_bf  = us; us += (size_t)B_*T_*N_*64;
  unsigned short* Qg     = us; us += (size_t)192*4*N_*8;
  unsigned short* Kg     = us; us += (size_t)192*4*352*8;
  unsigned short* Vg     = us; us += (size_t)192*4*11*512;
  unsigned short* Wcb    = us; us += 3*4*64*8;
  unsigned short* Wallb  = us; us += 2*4*144*8;
  unsigned short* Wpb    = us; us += 2*4*64*8;

  setup_hproj_k<<<36+1152,  256, 0, stream>>>(p1, pk, ind, A1, gmask_raw, bm, p3, p3t,
                                              W_gcn, b_gcn, W_r2, b_r2,
                                              Wtq, Wtk, Wtv, Wgq, Wgk, Wgv,
                                              W_proj, bc, Wcb, Wallb, Wpb,
                                              x, W_r1, b_r1, ht, hn);
  dg_adp      <<<B_*N_,     128, 0, stream>>>(p2, p3t, A1, adp_bf);
  gcn_mfma    <<<B_*36,     256, 0, stream>>>(adp_bf, ht,  x1t, x1n);
  gcn_mfma    <<<B_*36,     256, 0, stream>>>(adp_bf, x1t, (unsigned short*)nullptr, x2n);
  xg_k        <<<(B_*N_)/4, 256, 0, stream>>>(hn, x1n, x2n, Wcb, bc, xg_bf);
  qkv_k       <<<192*6,     256, 0, stream>>>(xg_bf, Wallb, qkv48, Qg, Kg, Vg);
  attn_fused  <<<4032+1300, 256, 0, stream>>>(qkv48, Qg, Kg, Vg, bm, att);
  proj_k      <<<(B_*T_*N_/16)/4, 256, 0, stream>>>(att, Wpb, b_proj, out);
}

// Round 17
// 162.262 us; speedup vs baseline: 1.1226x; 1.0356x over previous
//
#include <hip/hip_runtime.h>
#include <hip/hip_bf16.h>
#include <math.h>

#define B_ 16
#define T_ 12
#define N_ 325
#define DIMS_ 40
#define DAYS_ 288
#define MW 12          // bitmask words per mask row (11 used, 1 pad)
#define NQP 336        // padded q-rows for mask (21*16)
#define VP 352         // padded v/ct-row stride for transposed bf16 arrays (11*32)

typedef __attribute__((ext_vector_type(8))) short bf16x8;
typedef __attribute__((ext_vector_type(4))) float f32x4;

__device__ __forceinline__ unsigned short cvt1(float f){
  unsigned w;
  asm("v_cvt_pk_bf16_f32 %0, %1, %2" : "=v"(w) : "v"(f), "v"(f));
  return (unsigned short)w;
}
__device__ __forceinline__ unsigned cvt2(float a, float b){
  unsigned w;
  asm("v_cvt_pk_bf16_f32 %0, %1, %2" : "=v"(w) : "v"(a), "v"(b));
  return w;
}
__device__ __forceinline__ bf16x8 u2b(uint4 u){ return __builtin_bit_cast(bf16x8, u); }

// ---------------- fused setup ----------------
// blocks 0-15: dg_a1 | 16-31: mask_bits (inline dtype detect) | 32: p3 transpose
// blocks 33-35: weight prep (Wc/bc/Wcb, Wallb, Wpb)
__global__ void setup_k(const float* __restrict__ p1, const float* __restrict__ pk,
                        const int* __restrict__ ind, float* __restrict__ A1,
                        const unsigned char* __restrict__ raw, unsigned* __restrict__ bm,
                        const float* __restrict__ p3, float* __restrict__ p3t,
                        const float* W_gcn, const float* b_gcn, const float* W_r2, const float* b_r2,
                        const float* Wtq, const float* Wtk, const float* Wtv,
                        const float* Wgq, const float* Wgk, const float* Wgv,
                        const float* W_proj,
                        float* bc, unsigned short* Wcb, unsigned short* Wallb,
                        unsigned short* Wpb){
  int tid = threadIdx.x;
  if (blockIdx.x < 16){
    int b = blockIdx.x;
    __shared__ float te[DIMS_];
    int day = ind[b] % DAYS_; if (day < 0) day += DAYS_;
    for (int i = tid; i < DIMS_; i += blockDim.x) te[i] = p1[day*DIMS_ + i];
    __syncthreads();
    for (int jk = tid; jk < DIMS_*DIMS_; jk += blockDim.x){
      float acc = 0.f;
      for (int i = 0; i < DIMS_; ++i) acc += te[i] * pk[i*DIMS_*DIMS_ + jk];
      A1[b*DIMS_*DIMS_ + jk] = acc;
    }
  } else if (blockIdx.x < 32){
    __shared__ int f1, f3, fo;
    if (tid == 0){ f1 = 0; f3 = 0; fo = 0; }
    __syncthreads();
    for (int i = tid; i < 4096; i += 256){
      unsigned char v = raw[i];
      int m4 = i & 3;
      if (v == 0x3F && m4 == 1) atomicOr(&f1, 1);
      if (v == 0x3F && m4 == 3) atomicOr(&f3, 1);
      if (v != 0 && m4 != 0)    atomicOr(&fo, 1);
    }
    __syncthreads();
    int mode = f1 ? 2 : (f3 ? 3 : (fo ? 0 : 1));
    int idx = (blockIdx.x - 16) * 256 + tid;
    if (idx >= NQP * MW) return;
    int q = idx / MW, w = idx % MW;
    if (q >= N_) { bm[idx] = 0xFFFFFFFFu; return; }
    unsigned bits = 0;
    for (int j = 0; j < 32; ++j){
      int k = w*32 + j;
      int v;
      if (k >= N_) v = 1;
      else {
        size_t i = (size_t)q*N_ + k;
        if (mode == 0)      v = raw[i] != 0;
        else if (mode == 1) v = ((const int*)raw)[i] != 0;
        else if (mode == 2) { unsigned short u = ((const unsigned short*)raw)[i]; v = (u & 0x7FFF) != 0; }
        else                { float f = ((const float*)raw)[i]; v = (f != 0.f); }
      }
      bits |= (unsigned)v << j;
    }
    bm[idx] = bits;
  } else if (blockIdx.x == 32){
    for (int idx = tid; idx < DIMS_*N_; idx += 256){
      int k = idx / N_, c = idx % N_;
      p3t[idx] = p3[c*DIMS_ + k];
    }
  } else if (blockIdx.x == 33){
    __shared__ float WcS[64*96];
    for (int idx = tid; idx < 64*96; idx += 256){
      int d = idx / 96, c = idx % 96;
      float acc = 0.f;
      for (int o = 0; o < 32; ++o) acc += W_r2[d*32 + o] * W_gcn[o*96 + c];
      WcS[idx] = acc;
    }
    for (int d = tid; d < 64; d += 256){
      float acc = b_r2[d];
      for (int o = 0; o < 32; ++o) acc += W_r2[d*32 + o] * b_gcn[o];
      bc[d] = acc;
    }
    __syncthreads();
    for (int idx = tid; idx < 3*4*64*8; idx += 256){
      int jj = idx & 7, rest = idx >> 3;
      int d = rest % 64, gk = rest / 64;
      int g = gk & 3, kc = gk >> 2;
      Wcb[idx] = cvt1(WcS[d*96 + kc*32 + g*8 + jj]);
    }
  } else if (blockIdx.x == 34){
    for (int idx = tid; idx < 2*4*144*8; idx += 256){
      int jj = idx & 7, rest = idx >> 3;
      int j = rest % 144, gk = rest / 144;
      int g = gk & 3, kc = gk >> 2;
      int dd = kc*32 + g*8 + jj;
      const float* src; int rsrc;
      if      (j < 16) { src = Wtq; rsrc = j; }
      else if (j < 32) { src = Wtk; rsrc = j - 16; }
      else if (j < 48) { src = Wtv; rsrc = j - 32; }
      else if (j < 80) { src = Wgq; rsrc = j - 48; }
      else if (j < 112){ src = Wgk; rsrc = j - 80; }
      else             { src = Wgv; rsrc = j - 112; }
      Wallb[idx] = cvt1(src[rsrc*64 + dd]);
    }
  } else {
    for (int idx = tid; idx < 2*4*64*8; idx += 256){
      int jj = idx & 7, rest = idx >> 3;
      int d = rest % 64, gk = rest / 64;
      int g = gk & 3, kc = gk >> 2;
      int k = kc*32 + g*8 + jj;
      Wpb[idx] = (k < 48) ? cvt1(W_proj[d*48 + k]) : (unsigned short)0;
    }
  }
}

// ---------------- mid2: blocks [0,1152) hproj MFMA; [1152,6352) dg_adp (128-active, 256 thr) ----------------
// hproj and dg_adp are independent; co-residency overlaps MFMA-bound and latency-bound blocks.
__global__ __launch_bounds__(256) void mid2_k(const float* __restrict__ x,
                                              const float* __restrict__ W_r1,
                                              const float* __restrict__ b_r1,
                                              unsigned short* __restrict__ ht,
                                              unsigned short* __restrict__ hn,
                                              const float* __restrict__ p2,
                                              const float* __restrict__ p3t,
                                              const float* __restrict__ A1,
                                              unsigned short* __restrict__ adp_bf){
  __shared__ float p2r[DIMS_], t2[DIMS_], sbuf[N_], red[128];
  int tid = threadIdx.x, wv = tid >> 6, ln = tid & 63;
  int bid = blockIdx.x;
  if (bid < 1152){
    // ---- hproj MFMA (identical math to rounds 15/16, passed) ----
    int bt = bid / 6;
    int nt = (bid % 6)*4 + wv;
    if (nt >= 21) return;
    int g = ln >> 4, r = ln & 15;
    int n0 = nt*16;
    int nc = min(n0 + r, N_-1);
    int b = bt / T_, t = bt % T_;
    const float* xrow = x + ((size_t)bt*N_ + nc)*64;
    float4 xa = *(const float4*)&xrow[g*8];
    float4 xb = *(const float4*)&xrow[g*8 + 4];
    uint4 u0 = { cvt2(xa.x,xa.y), cvt2(xa.z,xa.w), cvt2(xb.x,xb.y), cvt2(xb.z,xb.w) };
    bf16x8 bv0 = u2b(u0);
    float4 xc = *(const float4*)&xrow[32 + g*8];
    float4 xd = *(const float4*)&xrow[32 + g*8 + 4];
    uint4 u1 = { cvt2(xc.x,xc.y), cvt2(xc.z,xc.w), cvt2(xd.x,xd.y), cvt2(xd.z,xd.w) };
    bf16x8 bv1 = u2b(u1);
    int n = n0 + r;
    #pragma unroll
    for (int ct = 0; ct < 2; ++ct){
      const float* wrow = W_r1 + (ct*16 + r)*64;
      float4 wa = *(const float4*)&wrow[g*8];
      float4 wb = *(const float4*)&wrow[g*8 + 4];
      uint4 ua = { cvt2(wa.x,wa.y), cvt2(wa.z,wa.w), cvt2(wb.x,wb.y), cvt2(wb.z,wb.w) };
      bf16x8 a0 = u2b(ua);
      float4 wc = *(const float4*)&wrow[32 + g*8];
      float4 wd = *(const float4*)&wrow[32 + g*8 + 4];
      uint4 ub = { cvt2(wc.x,wc.y), cvt2(wc.z,wc.w), cvt2(wd.x,wd.y), cvt2(wd.z,wd.w) };
      bf16x8 a1 = u2b(ub);
      f32x4 acc = {0.f,0.f,0.f,0.f};
      acc = __builtin_amdgcn_mfma_f32_16x16x32_bf16(a0, bv0, acc, 0,0,0);
      acc = __builtin_amdgcn_mfma_f32_16x16x32_bf16(a1, bv1, acc, 0,0,0);
      if (n < N_){
        float v0 = acc[0] + b_r1[ct*16 + g*4 + 0];
        float v1 = acc[1] + b_r1[ct*16 + g*4 + 1];
        float v2 = acc[2] + b_r1[ct*16 + g*4 + 2];
        float v3 = acc[3] + b_r1[ct*16 + g*4 + 3];
        int c0 = ct*16 + g*4;
        ht[((size_t)b*384 + t*32 + c0+0)*VP + n] = cvt1(v0);
        ht[((size_t)b*384 + t*32 + c0+1)*VP + n] = cvt1(v1);
        ht[((size_t)b*384 + t*32 + c0+2)*VP + n] = cvt1(v2);
        ht[((size_t)b*384 + t*32 + c0+3)*VP + n] = cvt1(v3);
        uint2 hp = { cvt2(v0, v1), cvt2(v2, v3) };
        *(uint2*)&hn[((size_t)b*N_ + n)*384 + t*32 + c0] = hp;
      }
    }
  } else {
    // ---- dg_adp: round-14 128-thread block body, lanes >=128 only join barriers ----
    int bid2 = bid - 1152;
    int b = bid2 / N_, n = bid2 % N_;
    bool act = (tid < 128);
    if (act && tid < DIMS_) p2r[tid] = p2[n*DIMS_ + tid];
    __syncthreads();
    if (act && tid < DIMS_){
      float acc = 0.f;
      const float* a1 = A1 + b*DIMS_*DIMS_;
      for (int j = 0; j < DIMS_; ++j) acc += p2r[j] * a1[j*DIMS_ + tid];
      t2[tid] = acc;
    }
    __syncthreads();
    float lm = -INFINITY;
    if (act){
      for (int c = tid; c < N_; c += 128){
        float acc = 0.f;
        for (int k = 0; k < DIMS_; ++k) acc += p3t[k*N_ + c] * t2[k];
        acc = fmaxf(acc, 0.f);
        sbuf[c] = acc; lm = fmaxf(lm, acc);
      }
      red[tid] = lm;
    }
    __syncthreads();
    for (int off = 64; off; off >>= 1){
      if (tid < off) red[tid] = fmaxf(red[tid], red[tid+off]);
      __syncthreads();
    }
    float m = red[0]; __syncthreads();
    float ls = 0.f;
    if (act){
      for (int c = tid; c < N_; c += 128){ float e = __expf(sbuf[c] - m); sbuf[c] = e; ls += e; }
      red[tid] = ls;
    }
    __syncthreads();
    for (int off = 64; off; off >>= 1){
      if (tid < off) red[tid] += red[tid+off];
      __syncthreads();
    }
    float inv = 1.f / red[0];
    if (act){
      unsigned short* outp = adp_bf + ((size_t)b*N_ + n) * VP;
      for (int c = tid; c < VP; c += 128)
        outp[c] = (c < N_) ? cvt1(sbuf[c] * inv) : (unsigned short)0;
    }
  }
}

// ---------------- GCN hop as MFMA GEMM; out_t (transposed, nullable) + out_n (row-major) ----------------
__global__ __launch_bounds__(256) void gcn_mfma(const unsigned short* __restrict__ adp_bf,
                                                const unsigned short* __restrict__ in_t,
                                                unsigned short* __restrict__ out_t,
                                                unsigned short* __restrict__ out_n){
  int bi = blockIdx.x;
  int b = bi / 36, rest = bi % 36;
  int wt = rest / 6, ctb = rest % 6;
  int tid = threadIdx.x, wv = tid >> 6, ln = tid & 63, g = ln >> 4, r = ln & 15;
  int w0 = wt*64 + wv*16;
  int ct0 = ctb*64;
  int wr = min(w0 + r, N_-1);
  const unsigned short* arow  = adp_bf + ((size_t)b*N_ + wr)*VP;
  const unsigned short* bbase = in_t  + ((size_t)b*384 + ct0)*VP;
  f32x4 acc0={0.f,0.f,0.f,0.f}, acc1=acc0, acc2=acc0, acc3=acc0;
  #pragma unroll
  for (int ks = 0; ks < 11; ++ks){
    int ko = ks*32 + g*8;
    bf16x8 a  = *(const bf16x8*)&arow[ko];
    bf16x8 b0 = *(const bf16x8*)&bbase[(size_t)( 0 + r)*VP + ko];
    bf16x8 b1 = *(const bf16x8*)&bbase[(size_t)(16 + r)*VP + ko];
    bf16x8 b2 = *(const bf16x8*)&bbase[(size_t)(32 + r)*VP + ko];
    bf16x8 b3 = *(const bf16x8*)&bbase[(size_t)(48 + r)*VP + ko];
    acc0 = __builtin_amdgcn_mfma_f32_16x16x32_bf16(a, b0, acc0, 0,0,0);
    acc1 = __builtin_amdgcn_mfma_f32_16x16x32_bf16(a, b1, acc1, 0,0,0);
    acc2 = __builtin_amdgcn_mfma_f32_16x16x32_bf16(a, b2, acc2, 0,0,0);
    acc3 = __builtin_amdgcn_mfma_f32_16x16x32_bf16(a, b3, acc3, 0,0,0);
  }
  f32x4 av[4] = {acc0, acc1, acc2, acc3};
  if (out_t && w0 + 15 < VP){
    #pragma unroll
    for (int dt = 0; dt < 4; ++dt){
      int ct = ct0 + dt*16 + r;
      uint2 pk2 = { cvt2(av[dt][0], av[dt][1]), cvt2(av[dt][2], av[dt][3]) };
      *(uint2*)&out_t[((size_t)b*384 + ct)*VP + w0 + g*4] = pk2;
    }
  }
  #pragma unroll
  for (int dt = 0; dt < 4; ++dt){
    int ct = ct0 + dt*16 + r;
    #pragma unroll
    for (int rg = 0; rg < 4; ++rg){
      int w = w0 + g*4 + rg;
      if (w < N_) out_n[((size_t)b*N_ + w)*384 + ct] = cvt1(av[dt][rg]);
    }
  }
}

// ---------------- xg: LDS-free MFMA GEMM per (b,n), row-major inputs ----------------
__global__ __launch_bounds__(256) void xg_k(const unsigned short* __restrict__ hn,
                                            const unsigned short* __restrict__ x1n,
                                            const unsigned short* __restrict__ x2n,
                                            const unsigned short* __restrict__ Wcb,
                                            const float* __restrict__ bc,
                                            unsigned short* __restrict__ xg_bf){
  int tid = threadIdx.x, wv = tid >> 6, ln = tid & 63;
  int p = blockIdx.x*4 + wv;
  int b = p / N_, n = p % N_;
  int g = ln >> 4, r = ln & 15;
  int rr = min(r, 11);
  size_t base = ((size_t)b*N_ + n)*384;
  bf16x8 a0 = *(const bf16x8*)&hn [base + rr*32 + g*8];
  bf16x8 a1 = *(const bf16x8*)&x1n[base + rr*32 + g*8];
  bf16x8 a2 = *(const bf16x8*)&x2n[base + rr*32 + g*8];
  #pragma unroll
  for (int dt = 0; dt < 4; ++dt){
    f32x4 acc = {0.f,0.f,0.f,0.f};
    bf16x8 b0 = *(const bf16x8*)&Wcb[((0*4+g)*64 + dt*16 + r)*8];
    bf16x8 b1 = *(const bf16x8*)&Wcb[((1*4+g)*64 + dt*16 + r)*8];
    bf16x8 b2 = *(const bf16x8*)&Wcb[((2*4+g)*64 + dt*16 + r)*8];
    acc = __builtin_amdgcn_mfma_f32_16x16x32_bf16(a0, b0, acc, 0,0,0);
    acc = __builtin_amdgcn_mfma_f32_16x16x32_bf16(a1, b1, acc, 0,0,0);
    acc = __builtin_amdgcn_mfma_f32_16x16x32_bf16(a2, b2, acc, 0,0,0);
    float bias = bc[dt*16 + r];
    if (g < 3){
      #pragma unroll
      for (int rg = 0; rg < 4; ++rg){
        int t = g*4 + rg;
        xg_bf[(((size_t)b*T_ + t)*N_ + n)*64 + dt*16 + r] = cvt1(acc[rg] + bias);
      }
    }
  }
}

// ---------------- qkv v2 (unchanged) ----------------
__global__ __launch_bounds__(256) void qkv_k(const unsigned short* __restrict__ xg_bf,
                                             const unsigned short* __restrict__ Wallb,
                                             float* __restrict__ qkv48,
                                             unsigned short* __restrict__ Qg,
                                             unsigned short* __restrict__ Kg,
                                             unsigned short* __restrict__ Vg){
  int tid = threadIdx.x, wv = tid >> 6, ln = tid & 63;
  int bt = blockIdx.x / 6;
  int nt = (blockIdx.x % 6)*4 + wv;
  if (nt >= 21) return;
  int g = ln >> 4, r = ln & 15;
  int n0 = nt*16;
  int nc = min(n0 + r, N_-1);
  const unsigned short* arow = xg_bf + ((size_t)bt*N_ + nc)*64;
  bf16x8 a0 = *(const bf16x8*)&arow[g*8];
  bf16x8 a1 = *(const bf16x8*)&arow[32 + g*8];
  const float kscale = 0.35355339059327373f * 1.4426950408889634f;
  int hh = r >> 3, dd = r & 7;
  #pragma unroll
  for (int jt = 0; jt < 9; ++jt){
    f32x4 acc = {0.f,0.f,0.f,0.f};
    bf16x8 b0 = *(const bf16x8*)&Wallb[((0*4+g)*144 + jt*16 + r)*8];
    bf16x8 b1 = *(const bf16x8*)&Wallb[((1*4+g)*144 + jt*16 + r)*8];
    acc = __builtin_amdgcn_mfma_f32_16x16x32_bf16(a0, b0, acc, 0,0,0);
    acc = __builtin_amdgcn_mfma_f32_16x16x32_bf16(a1, b1, acc, 0,0,0);
    #pragma unroll
    for (int rg = 0; rg < 4; ++rg){
      int n = n0 + g*4 + rg;
      if (n >= N_) continue;
      float v = acc[rg];
      if (jt < 3){
        qkv48[((size_t)bt*N_ + n)*48 + jt*16 + r] = v;
      } else if (jt < 5){
        int h = (jt-3)*2 + hh;
        Qg[(((size_t)bt*4 + h)*N_ + n)*8 + dd] = cvt1(v);
      } else if (jt < 7){
        int h = (jt-5)*2 + hh;
        Kg[(((size_t)bt*4 + h)*352 + n)*8 + dd] = cvt1(v * kscale);
      } else {
        int h = (jt-7)*2 + hh;
        int m = n & 31, ks = n >> 5;
        int p32 = (((m & 15) >> 2) << 3) | (m & 3) | ((m & 16) >> 2);
        Vg[(((size_t)bt*4 + h)*11 + ks)*512 + dd*32 + p32] = cvt1(v);
      }
    }
  }
}

// ---------------- fused attention: blocks [0,4032) = gattn v7, [4032,5332) = tattn ----------------
__global__ __launch_bounds__(256) void attn_fused(const float* __restrict__ qkv48,
                                                  const unsigned short* __restrict__ Qg,
                                                  const unsigned short* __restrict__ Kg,
                                                  const unsigned short* __restrict__ Vg,
                                                  const unsigned* __restrict__ bm,
                                                  float* __restrict__ att){
  __shared__ __align__(16) char smem[17408];
  int bid = blockIdx.x;
  int tid = threadIdx.x, wv = tid >> 6, ln = tid & 63;
  if (bid < 4032){
    int bt = (bid & 7)*24 + (bid >> 3)/21;
    int blkin = (bid >> 3) % 21;
    int unit = blkin*4 + wv;
    int h = unit / 21, tile = unit % 21;
    int g = ln >> 4, r = ln & 15, g4 = g*4;
    bool gzero = (g == 0);
    const bf16x8 z8 = {0,0,0,0,0,0,0,0};
    size_t hb = (size_t)bt*4 + h;
    int qb = tile*16;
    int qc = min(qb + r, N_-1);
    const uint4* bmp = (const uint4*)(bm + (size_t)(qb + r)*MW);
    uint4 m0 = bmp[0], m1 = bmp[1], m2 = bmp[2];
    unsigned bmw[11] = {m0.x,m0.y,m0.z,m0.w, m1.x,m1.y,m1.z,m1.w, m2.x,m2.y,m2.z};
    bf16x8 aq = z8;
    if (gzero) aq = *(const bf16x8*)&Qg[(hb*N_ + qc)*8];
    const unsigned short* Kh = Kg + hb*352*8;
    const unsigned short* Vh = Vg + hb*11*512;
    float ssum = 0.f;
    f32x4 acc = {0.f,0.f,0.f,0.f};
    #pragma unroll
    for (int ks = 0; ks < 11; ++ks){
      bf16x8 akA = z8, akB = z8;
      if (gzero){
        akA = *(const bf16x8*)&Kh[(ks*32 + r)*8];
        akB = *(const bf16x8*)&Kh[(ks*32 + 16 + r)*8];
      }
      f32x4 dA = {0.f,0.f,0.f,0.f}, dB = {0.f,0.f,0.f,0.f};
      dA = __builtin_amdgcn_mfma_f32_16x16x32_bf16(akA, aq, dA, 0,0,0);
      dB = __builtin_amdgcn_mfma_f32_16x16x32_bf16(akB, aq, dB, 0,0,0);
      unsigned wm = bmw[ks];
      unsigned bA = (wm >> g4) & 0xFu;
      unsigned bB = (wm >> (g4 + 16)) & 0xFu;
      float pA[4], pB[4];
      #pragma unroll
      for (int rg = 0; rg < 4; ++rg){
        float eA = exp2f(dA[rg]);
        float eB = exp2f(dB[rg]);
        eA = (bA & (1u << rg)) ? 0.f : eA;
        eB = (bB & (1u << rg)) ? 0.f : eB;
        ssum += eA; ssum += eB;
        pA[rg] = eA; pB[rg] = eB;
      }
      uint4 pw = { cvt2(pA[0],pA[1]), cvt2(pA[2],pA[3]),
                   cvt2(pB[0],pB[1]), cvt2(pB[2],pB[3]) };
      bf16x8 avv = *(const bf16x8*)&Vh[ks*512 + r*32 + g*8];
      acc = __builtin_amdgcn_mfma_f32_16x16x32_bf16(avv, u2b(pw), acc, 0,0,0);
    }
    ssum += __shfl_xor(ssum, 16);
    ssum += __shfl_xor(ssum, 32);
    float inv = (ssum > 0.f) ? __builtin_amdgcn_rcpf(ssum) : 0.f;
    int qq = qb + r;
    if (g < 2 && qq < N_){
      float4 o = make_float4(acc[0]*inv, acc[1]*inv, acc[2]*inv, acc[3]*inv);
      *(float4*)(att + ((size_t)bt*N_ + qq)*48 + 16 + h*8 + g4) = o;
    }
  } else {
    int p = (bid - 4032)*4 + wv;
    int b = p / N_, n = p % N_;
    float* qs = (float*)smem + (size_t)wv*576;
    float* ss = (float*)(smem + 9216) + (size_t)wv*288;
    for (int idx = ln; idx < T_*48; idx += 64){
      int t = idx / 48, j = idx % 48;
      qs[idx] = qkv48[(((size_t)b*T_ + t)*N_ + n)*48 + j];
    }
    const float scale = 0.35355339059327373f;
    for (int idx = ln; idx < 2*T_*T_; idx += 64){
      int hh = idx / 144, r2 = (idx / T_) % T_, c = idx % T_;
      float acc = 0.f;
      for (int d = 0; d < 8; ++d) acc += qs[r2*48 + hh*8 + d] * qs[c*48 + 16 + hh*8 + d];
      ss[idx] = acc * scale;
    }
    if (ln < 2*T_){
      int hh = ln / T_, r2 = ln % T_;
      float* row = ss + hh*144 + r2*T_;
      float m = -INFINITY; for (int k = 0; k < T_; ++k) m = fmaxf(m, row[k]);
      float s = 0.f; for (int k = 0; k < T_; ++k){ float e = __expf(row[k] - m); row[k] = e; s += e; }
      float inv = 1.f / s; for (int k = 0; k < T_; ++k) row[k] *= inv;
    }
    for (int idx = ln; idx < T_*16; idx += 64){
      int t = idx / 16, o = idx % 16; int hh = o / 8, d = o % 8;
      float acc = 0.f;
      const float* row = ss + hh*144 + t*T_;
      for (int k = 0; k < T_; ++k) acc += row[k] * qs[k*48 + 32 + hh*8 + d];
      att[(((size_t)b*T_ + t)*N_ + n)*48 + o] = acc;
    }
  }
}

// ---------------- final projection: MFMA GEMM (unchanged) ----------------
__global__ __launch_bounds__(256) void proj_k(const float* __restrict__ att,
                                              const unsigned short* __restrict__ Wpb,
                                              const float* __restrict__ b_proj,
                                              float* __restrict__ out){
  int tid = threadIdx.x, wv = tid >> 6, ln = tid & 63;
  int g = ln >> 4, r = ln & 15;
  long r0 = ((long)blockIdx.x*4 + wv)*16;
  const float* arow = att + (r0 + r)*48;
  float4 qa = *(const float4*)&arow[g*8];
  float4 qb = *(const float4*)&arow[g*8 + 4];
  uint4 u0 = { cvt2(qa.x,qa.y), cvt2(qa.z,qa.w), cvt2(qb.x,qb.y), cvt2(qb.z,qb.w) };
  bf16x8 a0 = u2b(u0);
  bf16x8 a1 = {0,0,0,0,0,0,0,0};
  if (g < 2){
    float4 qc = *(const float4*)&arow[32 + g*8];
    float4 qd = *(const float4*)&arow[36 + g*8];
    uint4 u1 = { cvt2(qc.x,qc.y), cvt2(qc.z,qc.w), cvt2(qd.x,qd.y), cvt2(qd.z,qd.w) };
    a1 = u2b(u1);
  }
  #pragma unroll
  for (int dt = 0; dt < 4; ++dt){
    f32x4 acc = {0.f,0.f,0.f,0.f};
    bf16x8 b0 = *(const bf16x8*)&Wpb[((0*4+g)*64 + dt*16 + r)*8];
    bf16x8 b1 = *(const bf16x8*)&Wpb[((1*4+g)*64 + dt*16 + r)*8];
    acc = __builtin_amdgcn_mfma_f32_16x16x32_bf16(a0, b0, acc, 0,0,0);
    acc = __builtin_amdgcn_mfma_f32_16x16x32_bf16(a1, b1, acc, 0,0,0);
    float bias = b_proj[dt*16 + r];
    #pragma unroll
    for (int rg = 0; rg < 4; ++rg)
      out[(r0 + g*4 + rg)*64 + dt*16 + r] = acc[rg] + bias;
  }
}

extern "C" void kernel_launch(void* const* d_in, const int* in_sizes, int n_in,
                              void* d_out, int out_size, void* d_ws, size_t ws_size,
                              hipStream_t stream){
  const float* x      = (const float*)d_in[0];
  const int*   ind    = (const int*)  d_in[1];
  const unsigned char* gmask_raw = (const unsigned char*)d_in[4];
  const float* p1     = (const float*)d_in[5];
  const float* p2     = (const float*)d_in[6];
  const float* p3     = (const float*)d_in[7];
  const float* pk     = (const float*)d_in[8];
  const float* W_r1   = (const float*)d_in[9];
  const float* b_r1   = (const float*)d_in[10];
  const float* W_gcn  = (const float*)d_in[11];
  const float* b_gcn  = (const float*)d_in[12];
  const float* W_r2   = (const float*)d_in[13];
  const float* b_r2   = (const float*)d_in[14];
  const float* Wtq    = (const float*)d_in[15];
  const float* Wtk    = (const float*)d_in[16];
  const float* Wtv    = (const float*)d_in[17];
  const float* Wgq    = (const float*)d_in[18];
  const float* Wgk    = (const float*)d_in[19];
  const float* Wgv    = (const float*)d_in[20];
  const float* W_proj = (const float*)d_in[21];
  const float* b_proj = (const float*)d_in[22];
  float* out = (float*)d_out;

  float* ws = (float*)d_ws;
  float* A1    = ws; ws += B_*DIMS_*DIMS_;
  float* bc    = ws; ws += 64;
  float* p3t   = ws; ws += DIMS_*N_;
  float* qkv48 = ws; ws += (size_t)B_*T_*N_*48;
  float* att   = ws; ws += (size_t)B_*T_*N_*48;
  unsigned* bm = (unsigned*)ws; ws += NQP*MW;
  unsigned short* us = (unsigned short*)ws;
  unsigned short* adp_bf = us; us += (size_t)B_*N_*VP;
  unsigned short* ht     = us; us += (size_t)B_*384*VP;
  unsigned short* x1t    = us; us += (size_t)B_*384*VP;
  unsigned short* hn     = us; us += (size_t)B_*N_*384;
  unsigned short* x1n    = us; us += (size_t)B_*N_*384;
  unsigned short* x2n    = us; us += (size_t)B_*N_*384;
  unsigned short* xg_bf  = us; us += (size_t)B_*T_*N_*64;
  unsigned short* Qg     = us; us += (size_t)192*4*N_*8;
  unsigned short* Kg     = us; us += (size_t)192*4*352*8;
  unsigned short* Vg     = us; us += (size_t)192*4*11*512;
  unsigned short* Wcb    = us; us += 3*4*64*8;
  unsigned short* Wallb  = us; us += 2*4*144*8;
  unsigned short* Wpb    = us; us += 2*4*64*8;

  setup_k     <<<36,        256, 0, stream>>>(p1, pk, ind, A1, gmask_raw, bm, p3, p3t,
                                              W_gcn, b_gcn, W_r2, b_r2,
                                              Wtq, Wtk, Wtv, Wgq, Wgk, Wgv,
                                              W_proj, bc, Wcb, Wallb, Wpb);
  mid2_k      <<<1152+B_*N_, 256, 0, stream>>>(x, W_r1, b_r1, ht, hn, p2, p3t, A1, adp_bf);
  gcn_mfma    <<<B_*36,     256, 0, stream>>>(adp_bf, ht,  x1t, x1n);
  gcn_mfma    <<<B_*36,     256, 0, stream>>>(adp_bf, x1t, (unsigned short*)nullptr, x2n);
  xg_k        <<<(B_*N_)/4, 256, 0, stream>>>(hn, x1n, x2n, Wcb, bc, xg_bf);
  qkv_k       <<<192*6,     256, 0, stream>>>(xg_bf, Wallb, qkv48, Qg, Kg, Vg);
  attn_fused  <<<4032+1300, 256, 0, stream>>>(qkv48, Qg, Kg, Vg, bm, att);
  proj_k      <<<(B_*T_*N_/16)/4, 256, 0, stream>>>(att, Wpb, b_proj, out);
}

// Round 18
// 153.843 us; speedup vs baseline: 1.1840x; 1.0547x over previous
//
#include <hip/hip_runtime.h>
#include <hip/hip_bf16.h>
#include <math.h>

#define B_ 16
#define T_ 12
#define N_ 325
#define DIMS_ 40
#define DAYS_ 288
#define MW 12          // bitmask words per mask row (11 used, 1 pad)
#define NQP 336        // padded q-rows for mask (21*16)
#define VP 352         // padded v/ct-row stride for transposed bf16 arrays (11*32)

typedef __attribute__((ext_vector_type(8))) short bf16x8;
typedef __attribute__((ext_vector_type(4))) float f32x4;

__device__ __forceinline__ unsigned short cvt1(float f){
  unsigned w;
  asm("v_cvt_pk_bf16_f32 %0, %1, %2" : "=v"(w) : "v"(f), "v"(f));
  return (unsigned short)w;
}
__device__ __forceinline__ unsigned cvt2(float a, float b){
  unsigned w;
  asm("v_cvt_pk_bf16_f32 %0, %1, %2" : "=v"(w) : "v"(a), "v"(b));
  return w;
}
__device__ __forceinline__ bf16x8 u2b(uint4 u){ return __builtin_bit_cast(bf16x8, u); }

// ---------------- fused setup ----------------
// blocks 0-15: dg_a1 | 16-31: mask_bits (inline dtype detect) | 32: p3 transpose
// blocks 33-36: weight prep (Wc/bc/Wcb, Wallb, Wpb, Wr1b)
__global__ void setup_k(const float* __restrict__ p1, const float* __restrict__ pk,
                        const int* __restrict__ ind, float* __restrict__ A1,
                        const unsigned char* __restrict__ raw, unsigned* __restrict__ bm,
                        const float* __restrict__ p3, float* __restrict__ p3t,
                        const float* W_gcn, const float* b_gcn, const float* W_r2, const float* b_r2,
                        const float* Wtq, const float* Wtk, const float* Wtv,
                        const float* Wgq, const float* Wgk, const float* Wgv,
                        const float* W_proj, const float* W_r1,
                        float* bc, unsigned short* Wcb, unsigned short* Wallb,
                        unsigned short* Wpb, unsigned short* Wr1b){
  int tid = threadIdx.x;
  if (blockIdx.x < 16){
    int b = blockIdx.x;
    __shared__ float te[DIMS_];
    int day = ind[b] % DAYS_; if (day < 0) day += DAYS_;
    for (int i = tid; i < DIMS_; i += blockDim.x) te[i] = p1[day*DIMS_ + i];
    __syncthreads();
    for (int jk = tid; jk < DIMS_*DIMS_; jk += blockDim.x){
      float acc = 0.f;
      for (int i = 0; i < DIMS_; ++i) acc += te[i] * pk[i*DIMS_*DIMS_ + jk];
      A1[b*DIMS_*DIMS_ + jk] = acc;
    }
  } else if (blockIdx.x < 32){
    // inline mask dtype detection (modes: 0=uint8, 1=int32, 2=bf16, 3=f32)
    __shared__ int f1, f3, fo;
    if (tid == 0){ f1 = 0; f3 = 0; fo = 0; }
    __syncthreads();
    for (int i = tid; i < 4096; i += 256){
      unsigned char v = raw[i];
      int m4 = i & 3;
      if (v == 0x3F && m4 == 1) atomicOr(&f1, 1);
      if (v == 0x3F && m4 == 3) atomicOr(&f3, 1);
      if (v != 0 && m4 != 0)    atomicOr(&fo, 1);
    }
    __syncthreads();
    int mode = f1 ? 2 : (f3 ? 3 : (fo ? 0 : 1));
    int idx = (blockIdx.x - 16) * 256 + tid;
    if (idx >= NQP * MW) return;
    int q = idx / MW, w = idx % MW;
    if (q >= N_) { bm[idx] = 0xFFFFFFFFu; return; }
    unsigned bits = 0;
    for (int j = 0; j < 32; ++j){
      int k = w*32 + j;
      int v;
      if (k >= N_) v = 1;
      else {
        size_t i = (size_t)q*N_ + k;
        if (mode == 0)      v = raw[i] != 0;
        else if (mode == 1) v = ((const int*)raw)[i] != 0;
        else if (mode == 2) { unsigned short u = ((const unsigned short*)raw)[i]; v = (u & 0x7FFF) != 0; }
        else                { float f = ((const float*)raw)[i]; v = (f != 0.f); }
      }
      bits |= (unsigned)v << j;
    }
    bm[idx] = bits;
  } else if (blockIdx.x == 32){
    for (int idx = tid; idx < DIMS_*N_; idx += 256){
      int k = idx / N_, c = idx % N_;
      p3t[idx] = p3[c*DIMS_ + k];
    }
  } else if (blockIdx.x == 33){
    __shared__ float WcS[64*96];
    for (int idx = tid; idx < 64*96; idx += 256){
      int d = idx / 96, c = idx % 96;
      float acc = 0.f;
      for (int o = 0; o < 32; ++o) acc += W_r2[d*32 + o] * W_gcn[o*96 + c];
      WcS[idx] = acc;
    }
    for (int d = tid; d < 64; d += 256){
      float acc = b_r2[d];
      for (int o = 0; o < 32; ++o) acc += W_r2[d*32 + o] * b_gcn[o];
      bc[d] = acc;
    }
    __syncthreads();
    for (int idx = tid; idx < 3*4*64*8; idx += 256){
      int jj = idx & 7, rest = idx >> 3;
      int d = rest % 64, gk = rest / 64;
      int g = gk & 3, kc = gk >> 2;
      Wcb[idx] = cvt1(WcS[d*96 + kc*32 + g*8 + jj]);
    }
  } else if (blockIdx.x == 34){
    for (int idx = tid; idx < 2*4*144*8; idx += 256){
      int jj = idx & 7, rest = idx >> 3;
      int j = rest % 144, gk = rest / 144;
      int g = gk & 3, kc = gk >> 2;
      int dd = kc*32 + g*8 + jj;
      const float* src; int rsrc;
      if      (j < 16) { src = Wtq; rsrc = j; }
      else if (j < 32) { src = Wtk; rsrc = j - 16; }
      else if (j < 48) { src = Wtv; rsrc = j - 32; }
      else if (j < 80) { src = Wgq; rsrc = j - 48; }
      else if (j < 112){ src = Wgk; rsrc = j - 80; }
      else             { src = Wgv; rsrc = j - 112; }
      Wallb[idx] = cvt1(src[rsrc*64 + dd]);
    }
  } else if (blockIdx.x == 35){
    for (int idx = tid; idx < 2*4*64*8; idx += 256){
      int jj = idx & 7, rest = idx >> 3;
      int d = rest % 64, gk = rest / 64;
      int g = gk & 3, kc = gk >> 2;
      int k = kc*32 + g*8 + jj;
      Wpb[idx] = (k < 48) ? cvt1(W_proj[d*48 + k]) : (unsigned short)0;
    }
  } else {
    for (int idx = tid; idx < 2*4*32*8; idx += 256){
      int jj = idx & 7, rest = idx >> 3;
      int c = rest % 32, gk = rest / 32;
      int g = gk & 3, kc = gk >> 2;
      Wr1b[idx] = cvt1(W_r1[c*64 + kc*32 + g*8 + jj]);
    }
  }
}

// adp_bf[b][n][c] bf16, row stride VP, cols >= N_ zeroed (pad-safe for MFMA K)
__global__ void dg_adp(const float* __restrict__ p2, const float* __restrict__ p3t,
                       const float* __restrict__ A1, unsigned short* __restrict__ adp_bf){
  int bid = blockIdx.x; int b = bid / N_; int n = bid % N_;
  __shared__ float p2r[DIMS_], t2[DIMS_], sbuf[N_], red[128];
  int tid = threadIdx.x;
  if (tid < DIMS_) p2r[tid] = p2[n*DIMS_ + tid];
  __syncthreads();
  if (tid < DIMS_){
    float acc = 0.f;
    const float* a1 = A1 + b*DIMS_*DIMS_;
    for (int j = 0; j < DIMS_; ++j) acc += p2r[j] * a1[j*DIMS_ + tid];
    t2[tid] = acc;
  }
  __syncthreads();
  float lm = -INFINITY;
  for (int c = tid; c < N_; c += 128){
    float acc = 0.f;
    for (int k = 0; k < DIMS_; ++k) acc += p3t[k*N_ + c] * t2[k];
    acc = fmaxf(acc, 0.f);
    sbuf[c] = acc; lm = fmaxf(lm, acc);
  }
  red[tid] = lm; __syncthreads();
  for (int off = 64; off; off >>= 1){ if (tid < off) red[tid] = fmaxf(red[tid], red[tid+off]); __syncthreads(); }
  float m = red[0]; __syncthreads();
  float ls = 0.f;
  for (int c = tid; c < N_; c += 128){ float e = __expf(sbuf[c] - m); sbuf[c] = e; ls += e; }
  red[tid] = ls; __syncthreads();
  for (int off = 64; off; off >>= 1){ if (tid < off) red[tid] += red[tid+off]; __syncthreads(); }
  float inv = 1.f / red[0];
  unsigned short* outp = adp_bf + ((size_t)b*N_ + n) * VP;
  for (int c = tid; c < VP; c += 128)
    outp[c] = (c < N_) ? cvt1(sbuf[c] * inv) : (unsigned short)0;
}

// ---------------- hproj as MFMA GEMM; writes ht (transposed) AND hn (row-major) ----------------
__global__ __launch_bounds__(256) void hproj_mfma(const float* __restrict__ x,
                                                  const unsigned short* __restrict__ Wr1b,
                                                  const float* __restrict__ b_r1,
                                                  unsigned short* __restrict__ ht,
                                                  unsigned short* __restrict__ hn){
  int tid = threadIdx.x, wv = tid >> 6, ln = tid & 63;
  int bt = blockIdx.x / 6;
  int nt = (blockIdx.x % 6)*4 + wv;
  if (nt >= 21) return;
  int g = ln >> 4, r = ln & 15;
  int n0 = nt*16;
  int nc = min(n0 + r, N_-1);
  int b = bt / T_, t = bt % T_;
  const float* xrow = x + ((size_t)bt*N_ + nc)*64;
  float4 xa = *(const float4*)&xrow[g*8];
  float4 xb = *(const float4*)&xrow[g*8 + 4];
  uint4 u0 = { cvt2(xa.x,xa.y), cvt2(xa.z,xa.w), cvt2(xb.x,xb.y), cvt2(xb.z,xb.w) };
  bf16x8 bv0 = u2b(u0);
  float4 xc = *(const float4*)&xrow[32 + g*8];
  float4 xd = *(const float4*)&xrow[32 + g*8 + 4];
  uint4 u1 = { cvt2(xc.x,xc.y), cvt2(xc.z,xc.w), cvt2(xd.x,xd.y), cvt2(xd.z,xd.w) };
  bf16x8 bv1 = u2b(u1);
  int n = n0 + r;
  #pragma unroll
  for (int ct = 0; ct < 2; ++ct){
    f32x4 acc = {0.f,0.f,0.f,0.f};
    bf16x8 a0 = *(const bf16x8*)&Wr1b[((0*4+g)*32 + ct*16 + r)*8];
    bf16x8 a1 = *(const bf16x8*)&Wr1b[((1*4+g)*32 + ct*16 + r)*8];
    acc = __builtin_amdgcn_mfma_f32_16x16x32_bf16(a0, bv0, acc, 0,0,0);
    acc = __builtin_amdgcn_mfma_f32_16x16x32_bf16(a1, bv1, acc, 0,0,0);
    if (n < N_){
      float v0 = acc[0] + b_r1[ct*16 + g*4 + 0];
      float v1 = acc[1] + b_r1[ct*16 + g*4 + 1];
      float v2 = acc[2] + b_r1[ct*16 + g*4 + 2];
      float v3 = acc[3] + b_r1[ct*16 + g*4 + 3];
      int c0 = ct*16 + g*4;
      ht[((size_t)b*384 + t*32 + c0+0)*VP + n] = cvt1(v0);
      ht[((size_t)b*384 + t*32 + c0+1)*VP + n] = cvt1(v1);
      ht[((size_t)b*384 + t*32 + c0+2)*VP + n] = cvt1(v2);
      ht[((size_t)b*384 + t*32 + c0+3)*VP + n] = cvt1(v3);
      uint2 hp = { cvt2(v0, v1), cvt2(v2, v3) };
      *(uint2*)&hn[((size_t)b*N_ + n)*384 + t*32 + c0] = hp;
    }
  }
}

// ---------------- GCN hop as MFMA GEMM; out_t (transposed, nullable) + out_n (row-major) ----------------
__global__ __launch_bounds__(256) void gcn_mfma(const unsigned short* __restrict__ adp_bf,
                                                const unsigned short* __restrict__ in_t,
                                                unsigned short* __restrict__ out_t,
                                                unsigned short* __restrict__ out_n){
  int bi = blockIdx.x;
  int b = bi / 36, rest = bi % 36;
  int wt = rest / 6, ctb = rest % 6;
  int tid = threadIdx.x, wv = tid >> 6, ln = tid & 63, g = ln >> 4, r = ln & 15;
  int w0 = wt*64 + wv*16;
  int ct0 = ctb*64;
  int wr = min(w0 + r, N_-1);
  const unsigned short* arow  = adp_bf + ((size_t)b*N_ + wr)*VP;
  const unsigned short* bbase = in_t  + ((size_t)b*384 + ct0)*VP;
  f32x4 acc0={0.f,0.f,0.f,0.f}, acc1=acc0, acc2=acc0, acc3=acc0;
  #pragma unroll
  for (int ks = 0; ks < 11; ++ks){
    int ko = ks*32 + g*8;
    bf16x8 a  = *(const bf16x8*)&arow[ko];
    bf16x8 b0 = *(const bf16x8*)&bbase[(size_t)( 0 + r)*VP + ko];
    bf16x8 b1 = *(const bf16x8*)&bbase[(size_t)(16 + r)*VP + ko];
    bf16x8 b2 = *(const bf16x8*)&bbase[(size_t)(32 + r)*VP + ko];
    bf16x8 b3 = *(const bf16x8*)&bbase[(size_t)(48 + r)*VP + ko];
    acc0 = __builtin_amdgcn_mfma_f32_16x16x32_bf16(a, b0, acc0, 0,0,0);
    acc1 = __builtin_amdgcn_mfma_f32_16x16x32_bf16(a, b1, acc1, 0,0,0);
    acc2 = __builtin_amdgcn_mfma_f32_16x16x32_bf16(a, b2, acc2, 0,0,0);
    acc3 = __builtin_amdgcn_mfma_f32_16x16x32_bf16(a, b3, acc3, 0,0,0);
  }
  f32x4 av[4] = {acc0, acc1, acc2, acc3};
  if (out_t && w0 + 15 < VP){
    #pragma unroll
    for (int dt = 0; dt < 4; ++dt){
      int ct = ct0 + dt*16 + r;
      uint2 pk2 = { cvt2(av[dt][0], av[dt][1]), cvt2(av[dt][2], av[dt][3]) };
      *(uint2*)&out_t[((size_t)b*384 + ct)*VP + w0 + g*4] = pk2;
    }
  }
  #pragma unroll
  for (int dt = 0; dt < 4; ++dt){
    int ct = ct0 + dt*16 + r;
    #pragma unroll
    for (int rg = 0; rg < 4; ++rg){
      int w = w0 + g*4 + rg;
      if (w < N_) out_n[((size_t)b*N_ + w)*384 + ct] = cvt1(av[dt][rg]);
    }
  }
}

// ---------------- xg: LDS-free MFMA GEMM per (b,n), row-major inputs ----------------
__global__ __launch_bounds__(256) void xg_k(const unsigned short* __restrict__ hn,
                                            const unsigned short* __restrict__ x1n,
                                            const unsigned short* __restrict__ x2n,
                                            const unsigned short* __restrict__ Wcb,
                                            const float* __restrict__ bc,
                                            unsigned short* __restrict__ xg_bf){
  int tid = threadIdx.x, wv = tid >> 6, ln = tid & 63;
  int p = blockIdx.x*4 + wv;
  int b = p / N_, n = p % N_;
  int g = ln >> 4, r = ln & 15;
  int rr = min(r, 11);
  size_t base = ((size_t)b*N_ + n)*384;
  bf16x8 a0 = *(const bf16x8*)&hn [base + rr*32 + g*8];
  bf16x8 a1 = *(const bf16x8*)&x1n[base + rr*32 + g*8];
  bf16x8 a2 = *(const bf16x8*)&x2n[base + rr*32 + g*8];
  #pragma unroll
  for (int dt = 0; dt < 4; ++dt){
    f32x4 acc = {0.f,0.f,0.f,0.f};
    bf16x8 b0 = *(const bf16x8*)&Wcb[((0*4+g)*64 + dt*16 + r)*8];
    bf16x8 b1 = *(const bf16x8*)&Wcb[((1*4+g)*64 + dt*16 + r)*8];
    bf16x8 b2 = *(const bf16x8*)&Wcb[((2*4+g)*64 + dt*16 + r)*8];
    acc = __builtin_amdgcn_mfma_f32_16x16x32_bf16(a0, b0, acc, 0,0,0);
    acc = __builtin_amdgcn_mfma_f32_16x16x32_bf16(a1, b1, acc, 0,0,0);
    acc = __builtin_amdgcn_mfma_f32_16x16x32_bf16(a2, b2, acc, 0,0,0);
    float bias = bc[dt*16 + r];
    if (g < 3){
      #pragma unroll
      for (int rg = 0; rg < 4; ++rg){
        int t = g*4 + rg;
        xg_bf[(((size_t)b*T_ + t)*N_ + n)*64 + dt*16 + r] = cvt1(acc[rg] + bias);
      }
    }
  }
}

// ---------------- qkv v2 ----------------
__global__ __launch_bounds__(256) void qkv_k(const unsigned short* __restrict__ xg_bf,
                                             const unsigned short* __restrict__ Wallb,
                                             float* __restrict__ qkv48,
                                             unsigned short* __restrict__ Qg,
                                             unsigned short* __restrict__ Kg,
                                             unsigned short* __restrict__ Vg){
  int tid = threadIdx.x, wv = tid >> 6, ln = tid & 63;
  int bt = blockIdx.x / 6;
  int nt = (blockIdx.x % 6)*4 + wv;
  if (nt >= 21) return;
  int g = ln >> 4, r = ln & 15;
  int n0 = nt*16;
  int nc = min(n0 + r, N_-1);
  const unsigned short* arow = xg_bf + ((size_t)bt*N_ + nc)*64;
  bf16x8 a0 = *(const bf16x8*)&arow[g*8];
  bf16x8 a1 = *(const bf16x8*)&arow[32 + g*8];
  const float kscale = 0.35355339059327373f * 1.4426950408889634f;
  int hh = r >> 3, dd = r & 7;
  #pragma unroll
  for (int jt = 0; jt < 9; ++jt){
    f32x4 acc = {0.f,0.f,0.f,0.f};
    bf16x8 b0 = *(const bf16x8*)&Wallb[((0*4+g)*144 + jt*16 + r)*8];
    bf16x8 b1 = *(const bf16x8*)&Wallb[((1*4+g)*144 + jt*16 + r)*8];
    acc = __builtin_amdgcn_mfma_f32_16x16x32_bf16(a0, b0, acc, 0,0,0);
    acc = __builtin_amdgcn_mfma_f32_16x16x32_bf16(a1, b1, acc, 0,0,0);
    #pragma unroll
    for (int rg = 0; rg < 4; ++rg){
      int n = n0 + g*4 + rg;
      if (n >= N_) continue;
      float v = acc[rg];
      if (jt < 3){
        qkv48[((size_t)bt*N_ + n)*48 + jt*16 + r] = v;
      } else if (jt < 5){
        int h = (jt-3)*2 + hh;
        Qg[(((size_t)bt*4 + h)*N_ + n)*8 + dd] = cvt1(v);
      } else if (jt < 7){
        int h = (jt-5)*2 + hh;
        Kg[(((size_t)bt*4 + h)*352 + n)*8 + dd] = cvt1(v * kscale);
      } else {
        int h = (jt-7)*2 + hh;
        int m = n & 31, ks = n >> 5;
        int p32 = (((m & 15) >> 2) << 3) | (m & 3) | ((m & 16) >> 2);
        Vg[(((size_t)bt*4 + h)*11 + ks)*512 + dd*32 + p32] = cvt1(v);
      }
    }
  }
}

// ---------------- fused attention: blocks [0,4032) = gattn v7, [4032,5332) = tattn ----------------
__global__ __launch_bounds__(256) void attn_fused(const float* __restrict__ qkv48,
                                                  const unsigned short* __restrict__ Qg,
                                                  const unsigned short* __restrict__ Kg,
                                                  const unsigned short* __restrict__ Vg,
                                                  const unsigned* __restrict__ bm,
                                                  float* __restrict__ att){
  __shared__ __align__(16) char smem[17408];
  int bid = blockIdx.x;
  int tid = threadIdx.x, wv = tid >> 6, ln = tid & 63;
  if (bid < 4032){
    int bt = (bid & 7)*24 + (bid >> 3)/21;
    int blkin = (bid >> 3) % 21;
    int unit = blkin*4 + wv;
    int h = unit / 21, tile = unit % 21;
    int g = ln >> 4, r = ln & 15, g4 = g*4;
    bool gzero = (g == 0);
    const bf16x8 z8 = {0,0,0,0,0,0,0,0};
    size_t hb = (size_t)bt*4 + h;
    int qb = tile*16;
    int qc = min(qb + r, N_-1);
    const uint4* bmp = (const uint4*)(bm + (size_t)(qb + r)*MW);
    uint4 m0 = bmp[0], m1 = bmp[1], m2 = bmp[2];
    unsigned bmw[11] = {m0.x,m0.y,m0.z,m0.w, m1.x,m1.y,m1.z,m1.w, m2.x,m2.y,m2.z};
    bf16x8 aq = z8;
    if (gzero) aq = *(const bf16x8*)&Qg[(hb*N_ + qc)*8];
    const unsigned short* Kh = Kg + hb*352*8;
    const unsigned short* Vh = Vg + hb*11*512;
    float ssum = 0.f;
    f32x4 acc = {0.f,0.f,0.f,0.f};
    #pragma unroll
    for (int ks = 0; ks < 11; ++ks){
      bf16x8 akA = z8, akB = z8;
      if (gzero){
        akA = *(const bf16x8*)&Kh[(ks*32 + r)*8];
        akB = *(const bf16x8*)&Kh[(ks*32 + 16 + r)*8];
      }
      f32x4 dA = {0.f,0.f,0.f,0.f}, dB = {0.f,0.f,0.f,0.f};
      dA = __builtin_amdgcn_mfma_f32_16x16x32_bf16(akA, aq, dA, 0,0,0);
      dB = __builtin_amdgcn_mfma_f32_16x16x32_bf16(akB, aq, dB, 0,0,0);
      unsigned wm = bmw[ks];
      unsigned bA = (wm >> g4) & 0xFu;
      unsigned bB = (wm >> (g4 + 16)) & 0xFu;
      float pA[4], pB[4];
      #pragma unroll
      for (int rg = 0; rg < 4; ++rg){
        float eA = exp2f(dA[rg]);
        float eB = exp2f(dB[rg]);
        eA = (bA & (1u << rg)) ? 0.f : eA;
        eB = (bB & (1u << rg)) ? 0.f : eB;
        ssum += eA; ssum += eB;
        pA[rg] = eA; pB[rg] = eB;
      }
      uint4 pw = { cvt2(pA[0],pA[1]), cvt2(pA[2],pA[3]),
                   cvt2(pB[0],pB[1]), cvt2(pB[2],pB[3]) };
      bf16x8 avv = *(const bf16x8*)&Vh[ks*512 + r*32 + g*8];
      acc = __builtin_amdgcn_mfma_f32_16x16x32_bf16(avv, u2b(pw), acc, 0,0,0);
    }
    ssum += __shfl_xor(ssum, 16);
    ssum += __shfl_xor(ssum, 32);
    float inv = (ssum > 0.f) ? __builtin_amdgcn_rcpf(ssum) : 0.f;
    int qq = qb + r;
    if (g < 2 && qq < N_){
      float4 o = make_float4(acc[0]*inv, acc[1]*inv, acc[2]*inv, acc[3]*inv);
      *(float4*)(att + ((size_t)bt*N_ + qq)*48 + 16 + h*8 + g4) = o;
    }
  } else {
    int p = (bid - 4032)*4 + wv;
    int b = p / N_, n = p % N_;
    float* qs = (float*)smem + (size_t)wv*576;
    float* ss = (float*)(smem + 9216) + (size_t)wv*288;
    for (int idx = ln; idx < T_*48; idx += 64){
      int t = idx / 48, j = idx % 48;
      qs[idx] = qkv48[(((size_t)b*T_ + t)*N_ + n)*48 + j];
    }
    const float scale = 0.35355339059327373f;
    for (int idx = ln; idx < 2*T_*T_; idx += 64){
      int hh = idx / 144, r2 = (idx / T_) % T_, c = idx % T_;
      float acc = 0.f;
      for (int d = 0; d < 8; ++d) acc += qs[r2*48 + hh*8 + d] * qs[c*48 + 16 + hh*8 + d];
      ss[idx] = acc * scale;
    }
    if (ln < 2*T_){
      int hh = ln / T_, r2 = ln % T_;
      float* row = ss + hh*144 + r2*T_;
      float m = -INFINITY; for (int k = 0; k < T_; ++k) m = fmaxf(m, row[k]);
      float s = 0.f; for (int k = 0; k < T_; ++k){ float e = __expf(row[k] - m); row[k] = e; s += e; }
      float inv = 1.f / s; for (int k = 0; k < T_; ++k) row[k] *= inv;
    }
    for (int idx = ln; idx < T_*16; idx += 64){
      int t = idx / 16, o = idx % 16; int hh = o / 8, d = o % 8;
      float acc = 0.f;
      const float* row = ss + hh*144 + t*T_;
      for (int k = 0; k < T_; ++k) acc += row[k] * qs[k*48 + 32 + hh*8 + d];
      att[(((size_t)b*T_ + t)*N_ + n)*48 + o] = acc;
    }
  }
}

// ---------------- final projection: MFMA GEMM ----------------
__global__ __launch_bounds__(256) void proj_k(const float* __restrict__ att,
                                              const unsigned short* __restrict__ Wpb,
                                              const float* __restrict__ b_proj,
                                              float* __restrict__ out){
  int tid = threadIdx.x, wv = tid >> 6, ln = tid & 63;
  int g = ln >> 4, r = ln & 15;
  long r0 = ((long)blockIdx.x*4 + wv)*16;
  const float* arow = att + (r0 + r)*48;
  float4 qa = *(const float4*)&arow[g*8];
  float4 qb = *(const float4*)&arow[g*8 + 4];
  uint4 u0 = { cvt2(qa.x,qa.y), cvt2(qa.z,qa.w), cvt2(qb.x,qb.y), cvt2(qb.z,qb.w) };
  bf16x8 a0 = u2b(u0);
  bf16x8 a1 = {0,0,0,0,0,0,0,0};
  if (g < 2){
    float4 qc = *(const float4*)&arow[32 + g*8];
    float4 qd = *(const float4*)&arow[36 + g*8];
    uint4 u1 = { cvt2(qc.x,qc.y), cvt2(qc.z,qc.w), cvt2(qd.x,qd.y), cvt2(qd.z,qd.w) };
    a1 = u2b(u1);
  }
  #pragma unroll
  for (int dt = 0; dt < 4; ++dt){
    f32x4 acc = {0.f,0.f,0.f,0.f};
    bf16x8 b0 = *(const bf16x8*)&Wpb[((0*4+g)*64 + dt*16 + r)*8];
    bf16x8 b1 = *(const bf16x8*)&Wpb[((1*4+g)*64 + dt*16 + r)*8];
    acc = __builtin_amdgcn_mfma_f32_16x16x32_bf16(a0, b0, acc, 0,0,0);
    acc = __builtin_amdgcn_mfma_f32_16x16x32_bf16(a1, b1, acc, 0,0,0);
    float bias = b_proj[dt*16 + r];
    #pragma unroll
    for (int rg = 0; rg < 4; ++rg)
      out[(r0 + g*4 + rg)*64 + dt*16 + r] = acc[rg] + bias;
  }
}

extern "C" void kernel_launch(void* const* d_in, const int* in_sizes, int n_in,
                              void* d_out, int out_size, void* d_ws, size_t ws_size,
                              hipStream_t stream){
  const float* x      = (const float*)d_in[0];
  const int*   ind    = (const int*)  d_in[1];
  const unsigned char* gmask_raw = (const unsigned char*)d_in[4];
  const float* p1     = (const float*)d_in[5];
  const float* p2     = (const float*)d_in[6];
  const float* p3     = (const float*)d_in[7];
  const float* pk     = (const float*)d_in[8];
  const float* W_r1   = (const float*)d_in[9];
  const float* b_r1   = (const float*)d_in[10];
  const float* W_gcn  = (const float*)d_in[11];
  const float* b_gcn  = (const float*)d_in[12];
  const float* W_r2   = (const float*)d_in[13];
  const float* b_r2   = (const float*)d_in[14];
  const float* Wtq    = (const float*)d_in[15];
  const float* Wtk    = (const float*)d_in[16];
  const float* Wtv    = (const float*)d_in[17];
  const float* Wgq    = (const float*)d_in[18];
  const float* Wgk    = (const float*)d_in[19];
  const float* Wgv    = (const float*)d_in[20];
  const float* W_proj = (const float*)d_in[21];
  const float* b_proj = (const float*)d_in[22];
  float* out = (float*)d_out;

  float* ws = (float*)d_ws;
  float* A1    = ws; ws += B_*DIMS_*DIMS_;
  float* bc    = ws; ws += 64;
  float* p3t   = ws; ws += DIMS_*N_;
  float* qkv48 = ws; ws += (size_t)B_*T_*N_*48;
  float* att   = ws; ws += (size_t)B_*T_*N_*48;
  unsigned* bm = (unsigned*)ws; ws += NQP*MW;
  unsigned short* us = (unsigned short*)ws;
  unsigned short* adp_bf = us; us += (size_t)B_*N_*VP;
  unsigned short* ht     = us; us += (size_t)B_*384*VP;
  unsigned short* x1t    = us; us += (size_t)B_*384*VP;
  unsigned short* hn     = us; us += (size_t)B_*N_*384;
  unsigned short* x1n    = us; us += (size_t)B_*N_*384;
  unsigned short* x2n    = us; us += (size_t)B_*N_*384;
  unsigned short* xg_bf  = us; us += (size_t)B_*T_*N_*64;
  unsigned short* Qg     = us; us += (size_t)192*4*N_*8;
  unsigned short* Kg     = us; us += (size_t)192*4*352*8;
  unsigned short* Vg     = us; us += (size_t)192*4*11*512;
  unsigned short* Wcb    = us; us += 3*4*64*8;
  unsigned short* Wallb  = us; us += 2*4*144*8;
  unsigned short* Wpb    = us; us += 2*4*64*8;
  unsigned short* Wr1b   = us; us += 2*4*32*8;

  setup_k     <<<37,        256, 0, stream>>>(p1, pk, ind, A1, gmask_raw, bm, p3, p3t,
                                              W_gcn, b_gcn, W_r2, b_r2,
                                              Wtq, Wtk, Wtv, Wgq, Wgk, Wgv,
                                              W_proj, W_r1, bc, Wcb, Wallb, Wpb, Wr1b);
  dg_adp      <<<B_*N_,     128, 0, stream>>>(p2, p3t, A1, adp_bf);
  hproj_mfma  <<<192*6,     256, 0, stream>>>(x, Wr1b, b_r1, ht, hn);
  gcn_mfma    <<<B_*36,     256, 0, stream>>>(adp_bf, ht,  x1t, x1n);
  gcn_mfma    <<<B_*36,     256, 0, stream>>>(adp_bf, x1t, (unsigned short*)nullptr, x2n);
  xg_k        <<<(B_*N_)/4, 256, 0, stream>>>(hn, x1n, x2n, Wcb, bc, xg_bf);
  qkv_k       <<<192*6,     256, 0, stream>>>(xg_bf, Wallb, qkv48, Qg, Kg, Vg);
  attn_fused  <<<4032+1300, 256, 0, stream>>>(qkv48, Qg, Kg, Vg, bm, att);
  proj_k      <<<(B_*T_*N_/16)/4, 256, 0, stream>>>(att, Wpb, b_proj, out);
}